// Round 11
// baseline (798.723 us; speedup 1.0000x reference)
//
#include <hip/hip_runtime.h>

// ---------------------------------------------------------------------------
// GAE_IR_79499844649397. Atomic-free pipeline.
// Big GEMMs: 128x128 tile, 4 waves, BK=32, TRIPLE-buffered LDS (48KB) with
// distance-2 prefetch + ONE s_barrier/iter + vmcnt(8) steady-state.
// Slot-XOR swizzle, 3 blocks/CU, 1-D grid, XCD chunked swizzle.
// ---------------------------------------------------------------------------

typedef unsigned short u16;
typedef __bf16 bf16x8 __attribute__((ext_vector_type(8)));
typedef float f32x4 __attribute__((ext_vector_type(4)));

__device__ inline u16 f2bf_u(float f) {
  union { float f; unsigned u; } a; a.f = f;
  unsigned u = a.u + 0x7fffu + ((a.u >> 16) & 1u);   // RNE
  return (u16)(u >> 16);
}
__device__ inline float bf2f_u(u16 h) {
  union { unsigned u; float f; } a; a.u = ((unsigned)h) << 16; return a.f;
}

#define GLOAD16(gptr, lptr)                                                   \
  __builtin_amdgcn_global_load_lds(                                           \
      (__attribute__((address_space(1))) void*)(gptr),                        \
      (__attribute__((address_space(3))) void*)(lptr), 16, 0, 0)

#define BAR  __builtin_amdgcn_s_barrier()
#define FENCE asm volatile("" ::: "memory")
#define VMC8 asm volatile("s_waitcnt vmcnt(8)" ::: "memory")
#define VMC4 asm volatile("s_waitcnt vmcnt(4)" ::: "memory")
#define VMC0 asm volatile("s_waitcnt vmcnt(0)" ::: "memory")

struct Panel {
  const u16* A; int lda;
  const u16* B; int ldb;
  const float* bias; int biasN;
  int N; int nK;               // nK in units of 32
  void* out; int ldc;
  const float* rsVec;          // optional per-row scale (pre-rsqrt'd)
  const float* addS;           // optional gathered row-add (f32, ld 4096)
  int gx;                      // col-blocks (N tiles of 128)
  int rowG0;                   // global row offset of this panel
};

// MODE 0: bf16 out, v = relu(acc*rs + bias + S[b])
// MODE 1: bf16 out + bias, + rowsq partials
// MODE 3: f32 out + bias, 3-range remap + rowsq partials
template <int MODE>
__global__ __launch_bounds__(256, 3) void gemm128(
    Panel p0, Panel p1, int c0,
    float* __restrict__ rsPart, int rsLd,
    float* __restrict__ cTheta, float* __restrict__ cNeg, float* __restrict__ cTgt) {
  __shared__ u16 As[3][4096];   // [128][32] x3 buf
  __shared__ u16 Bs[3][4096];

  // chunked-bijective XCD swizzle (1-D grid)
  const int nwg = gridDim.x;
  const int orig = blockIdx.x;
  const int q = nwg >> 3, r = nwg & 7, xcd = orig & 7;
  const int basewg = (xcd < r) ? xcd * (q + 1) : r * (q + 1) + (xcd - r) * q;
  const int wg = basewg + (orig >> 3);

  Panel P; int pby, pbx;
  if (wg < c0) { P = p0; pby = wg / p0.gx; pbx = wg - pby * p0.gx; }
  else { P = p1; const int w2 = wg - c0; pby = w2 / p1.gx; pbx = w2 - pby * p1.gx; }
  const int m0 = pby << 7, n0 = pbx << 7;

  const int tid = threadIdx.x;
  const int wave = tid >> 6, lane = tid & 63;
  const int lr = lane & 15, lg = lane >> 4;
  const int wr = wave >> 1, wc = wave & 1;

  f32x4 acc[4][4] = {};

  // staging with slot-XOR swizzle: LDS[row][sc] = G[row][sc ^ ((row>>1)&3)]
  const int r0 = tid >> 2, sc0 = tid & 3;
  const size_t aOff  = (size_t)(m0 + r0) * P.lda + ((sc0 ^ ((r0 >> 1) & 3)) << 3);
  const size_t aOff1 = (size_t)(m0 + r0 + 64) * P.lda + ((sc0 ^ (((r0 + 64) >> 1) & 3)) << 3);
  const size_t bOff  = (size_t)(n0 + r0) * P.ldb + ((sc0 ^ ((r0 >> 1) & 3)) << 3);
  const size_t bOff1 = (size_t)(n0 + r0 + 64) * P.ldb + ((sc0 ^ (((r0 + 64) >> 1) & 3)) << 3);
  const int lL = (r0 * 4 + sc0) << 4;   // byte offset within buffer (linear dest)

  auto stage = [&](int kt, int b) {
    const int k0 = kt << 5;
    GLOAD16(P.A + aOff + k0, (char*)As[b] + lL);
    GLOAD16(P.A + aOff1 + k0, (char*)As[b] + lL + 4096);
    GLOAD16(P.B + bOff + k0, (char*)Bs[b] + lL);
    GLOAD16(P.B + bOff1 + k0, (char*)Bs[b] + lL + 4096);
  };

  const int nK = P.nK;

  auto iter = [&](int kt, int cb) {
    BAR; FENCE;
    // stage(kt+2) overwrites buf (cb+2)%3 == buf of tile kt-1, whose reads
    // completed before any wave passed this barrier (MFMA issue requires them).
    if (kt + 2 < nK) { stage(kt + 2, (cb + 2) % 3); VMC8; }  // tile kt landed
    else if (kt + 1 < nK) { VMC4; }
    else { VMC0; }
    FENCE;
    bf16x8 af[4], bv[4];
#pragma unroll
    for (int m = 0; m < 4; ++m) {
      const int row = (wr << 6) + (m << 4) + lr;
      af[m] = *(const bf16x8*)(&As[cb][row * 32 + ((lg ^ ((row >> 1) & 3)) << 3)]);
    }
#pragma unroll
    for (int n = 0; n < 4; ++n) {
      const int row = (wc << 6) + (n << 4) + lr;
      bv[n] = *(const bf16x8*)(&Bs[cb][row * 32 + ((lg ^ ((row >> 1) & 3)) << 3)]);
    }
#pragma unroll
    for (int m = 0; m < 4; ++m)
#pragma unroll
      for (int n = 0; n < 4; ++n)
        acc[m][n] = __builtin_amdgcn_mfma_f32_16x16x32_bf16(af[m], bv[n], acc[m][n], 0, 0, 0);
  };

  stage(0, 0);
  if (nK > 1) stage(1, 1);
  for (int kt = 0; kt < nK; kt += 3) {
    iter(kt, 0);
    if (kt + 1 < nK) iter(kt + 1, 1);
    if (kt + 2 < nK) iter(kt + 2, 2);
  }

  const int gcb = n0 + (wc << 6);
  const int grb = m0 + (wr << 6) + (lg << 2);
#pragma unroll
  for (int m = 0; m < 4; ++m) {
#pragma unroll
    for (int rr = 0; rr < 4; ++rr) {
      const int grow = grb + (m << 4) + rr;
      const int growG = P.rowG0 + grow;
      float ss = 0.f;
      float rs = 1.f;
      const float* Sp = nullptr;
      if (MODE == 0) {
        if (P.rsVec) rs = P.rsVec[growG];
        if (P.addS) {
          int bv2 = (growG < 256) ? growG : (growG - 256) / 114;
          Sp = P.addS + (size_t)bv2 * 4096;
        }
      }
#pragma unroll
      for (int n = 0; n < 4; ++n) {
        const int gc = gcb + (n << 4) + lr;
        if (gc >= P.N) continue;
        float v = acc[m][n][rr];
        if (MODE == 0) {
          v *= rs;
          if (gc < P.biasN) v += P.bias[gc];
          if (Sp) v += Sp[gc];
          v = fmaxf(v, 0.f);
          ((u16*)P.out)[(size_t)grow * P.ldc + gc] = f2bf_u(v);
        } else if (MODE == 1) {
          if (gc < P.biasN) v += P.bias[gc];
          ((u16*)P.out)[(size_t)grow * P.ldc + gc] = f2bf_u(v);
          ss += v * v;
        } else {
          if (gc < P.biasN) v += P.bias[gc];
          float* op = (growG < 256) ? cTheta + (size_t)growG * 800
                    : (growG < 29440) ? cNeg + (size_t)(growG - 256) * 800
                                      : cTgt + (size_t)(growG - 29440) * 800;
          op[gc] = v;
          ss += v * v;
        }
      }
      if (MODE == 1 || MODE == 3) {
        ss += __shfl_xor(ss, 1); ss += __shfl_xor(ss, 2);
        ss += __shfl_xor(ss, 4); ss += __shfl_xor(ss, 8);
        if (lr == 0) rsPart[(size_t)((pbx << 1) + wc) * rsLd + growG] = ss;
      }
    }
  }
}

// ---------------------------------------------------------------------------
// Small-M GEMM: 128x128, BK=32. STORE=1 plain store; else z-partial store.
// ---------------------------------------------------------------------------
template <int STORE>
__global__ __launch_bounds__(256) void gemm_atom(
    const u16* __restrict__ A, int lda, const u16* __restrict__ Bt, int ldb,
    int N, int nK, int ktChunk, float* __restrict__ Cf, int ldc, int zStride) {
  __shared__ u16 As[2][4096];
  __shared__ u16 Bs[2][4096];
  const int tid = threadIdx.x;
  const int wave = tid >> 6, lane = tid & 63;
  const int lr = lane & 15, lg = lane >> 4;
  const int wr = wave >> 1, wc = wave & 1;
  const int m0 = blockIdx.y << 7, n0 = blockIdx.x << 7;

  f32x4 acc[4][4] = {};

  const size_t aOff  = (size_t)(m0 + (tid >> 2)) * lda + ((tid & 3) << 3);
  const size_t aOff1 = aOff + (size_t)64 * lda;
  const size_t bOff  = (size_t)(n0 + (tid >> 2)) * ldb + ((tid & 3) << 3);
  const size_t bOff1 = bOff + (size_t)64 * ldb;

  const int kt0 = blockIdx.z * ktChunk;
  int ktEnd = kt0 + ktChunk; if (ktEnd > nK) ktEnd = nK;

  auto stage = [&](int kt, int b) {
    const int k0 = kt << 5;
    u16* Ad = &As[b][wave << 9];
    u16* Bd = &Bs[b][wave << 9];
    GLOAD16(A + aOff + k0, Ad);
    GLOAD16(A + aOff1 + k0, Ad + 2048);
    GLOAD16(Bt + bOff + k0, Bd);
    GLOAD16(Bt + bOff1 + k0, Bd + 2048);
  };

  if (kt0 < ktEnd) stage(kt0, 0);
  for (int kt = kt0; kt < ktEnd; ++kt) {
    const int cb = (kt - kt0) & 1;
    if (kt + 1 < ktEnd) {
      stage(kt + 1, cb ^ 1);
      VMC4;
    } else {
      VMC0;
    }
    BAR;
    FENCE;

    bf16x8 af[4], bvv[4];
#pragma unroll
    for (int m = 0; m < 4; ++m)
      af[m] = *(const bf16x8*)(&As[cb][(((wr << 6) + (m << 4) + lr) << 5) + (lg << 3)]);
#pragma unroll
    for (int n = 0; n < 4; ++n)
      bvv[n] = *(const bf16x8*)(&Bs[cb][(((wc << 6) + (n << 4) + lr) << 5) + (lg << 3)]);
#pragma unroll
    for (int m = 0; m < 4; ++m)
#pragma unroll
      for (int n = 0; n < 4; ++n)
        acc[m][n] = __builtin_amdgcn_mfma_f32_16x16x32_bf16(af[m], bvv[n], acc[m][n], 0, 0, 0);

    asm volatile("s_waitcnt lgkmcnt(0)" ::: "memory");
    BAR;
    FENCE;
  }

  float* out = STORE ? Cf : (Cf + (size_t)blockIdx.z * zStride);
  const int gcb = n0 + (wc << 6);
  const int grb = m0 + (wr << 6) + (lg << 2);
#pragma unroll
  for (int m = 0; m < 4; ++m)
#pragma unroll
    for (int rr = 0; rr < 4; ++rr) {
      const int grow = grb + (m << 4) + rr;
#pragma unroll
      for (int n = 0; n < 4; ++n) {
        const int gc = gcb + (n << 4) + lr;
        if (gc < N) out[(size_t)grow * ldc + gc] = acc[m][n][rr];
      }
    }
}

// --------------------------- weight packing --------------------------------
struct PJob { const float* src; u16* dst; int Ksrc, Nsrc, Kpad, Npad, ld; };
struct PJobs { PJob j[10]; };

__global__ void k_pack10(PJobs J) {
  PJob job = J.j[blockIdx.z];
  const int k0 = blockIdx.x * 16, n0 = blockIdx.y * 16;
  if (k0 >= job.Kpad || n0 >= job.Npad) return;
  __shared__ float t[16][17];
  const int tx = threadIdx.x, ty = threadIdx.y;
  const int km = k0 + ty, n = n0 + tx;
  float v = (km < job.Ksrc && n < job.Nsrc) ? job.src[(size_t)km * job.Nsrc + n] : 0.f;
  t[ty][tx] = v;
  __syncthreads();
  if (k0 + tx < job.Kpad && n0 + ty < job.Npad)
    job.dst[(size_t)(n0 + ty) * job.ld + k0 + tx] = f2bf_u(t[tx][ty]);
}

// Split-bf16 stacked pack: W[Ktot][Nsrc] = [srcA(splitK); srcB]; k blocks [hi,hi,lo].
__global__ void k_pack_split(const float* __restrict__ srcA, const float* __restrict__ srcB,
                             int splitK, int Ktot, int Nsrc,
                             u16* __restrict__ dst, int dstLd) {
  __shared__ float t[16][17];
  const int k0 = blockIdx.x * 16, n0 = blockIdx.y * 16;
  const int tx = threadIdx.x, ty = threadIdx.y;
  int kOut = k0 + ty;
  int blk = kOut / Ktot; int km = kOut - blk * Ktot;
  const int n = n0 + tx;
  float v = 0.f;
  if (n < Nsrc)
    v = (km < splitK) ? srcA[(size_t)km * Nsrc + n]
                      : srcB[(size_t)(km - splitK) * Nsrc + n];
  t[ty][tx] = v;
  __syncthreads();
  const int kw = k0 + tx;
  const int blkw = kw / Ktot;
  float x = t[tx][ty];
  u16 hb = f2bf_u(x);
  u16 o = (blkw == 2) ? f2bf_u(x - bf2f_u(hb)) : hb;
  dst[(size_t)(n0 + ty) * dstLd + kw] = o;
}

// ---------------- SAGE aggregation (atomic-free per-node scan) -------------
__global__ void k_aggpack1(const int* __restrict__ es, const int* __restrict__ ed,
                           const float* __restrict__ nodes, u16* __restrict__ Agp) {
  const int node = blockIdx.x;              // 0..383
  const int c = threadIdx.x * 2;
  u16* row = Agp + (size_t)node * 3072;
  if (node >= 360) {
#pragma unroll
    for (int b = 0; b < 3; ++b) { row[b * 1024 + c] = 0; row[b * 1024 + c + 1] = 0;
                                  row[b * 1024 + 512 + c] = 0; row[b * 1024 + 512 + c + 1] = 0; }
    return;
  }
  float a0 = 0.f, a1 = 0.f, cnt = 0.f;
  for (int e = 0; e < 1262; ++e) {
    if (ed[e] == node) {
      const float* xr = nodes + (size_t)es[e] * 512;
      a0 += xr[c]; a1 += xr[c + 1]; cnt += 1.f;
    }
  }
  float inv = 1.f / fmaxf(cnt, 1.f);
  a0 *= inv; a1 *= inv;
  float x0 = nodes[(size_t)node * 512 + c], x1 = nodes[(size_t)node * 512 + c + 1];
  u16 ah0 = f2bf_u(a0), ah1 = f2bf_u(a1);
  u16 al0 = f2bf_u(a0 - bf2f_u(ah0)), al1 = f2bf_u(a1 - bf2f_u(ah1));
  u16 xh0 = f2bf_u(x0), xh1 = f2bf_u(x1);
  u16 xl0 = f2bf_u(x0 - bf2f_u(xh0)), xl1 = f2bf_u(x1 - bf2f_u(xh1));
  row[c] = ah0; row[c + 1] = ah1; row[512 + c] = xh0; row[512 + c + 1] = xh1;
  row[1024 + c] = al0; row[1024 + c + 1] = al1; row[1536 + c] = xl0; row[1536 + c + 1] = xl1;
  row[2048 + c] = ah0; row[2048 + c + 1] = ah1; row[2560 + c] = xh0; row[2560 + c + 1] = xh1;
}

__global__ void k_aggpack2(const int* __restrict__ es, const int* __restrict__ ed,
                           const float* __restrict__ Hf, u16* __restrict__ A2p) {
  const int node = blockIdx.x;              // 0..383
  const int c = threadIdx.x * 8;
  u16* row = A2p + (size_t)node * 12288;
  if (node >= 360) {
#pragma unroll
    for (int b = 0; b < 3; ++b)
      for (int j = 0; j < 8; ++j) { row[b * 4096 + c + j] = 0; row[b * 4096 + 2048 + c + j] = 0; }
    return;
  }
  float a[8] = {}; float cnt = 0.f;
  for (int e = 0; e < 1262; ++e) {
    if (ed[e] == node) {
      const float* hr = Hf + (size_t)es[e] * 2048 + c;
      float4 v0 = *(const float4*)hr, v1 = *(const float4*)(hr + 4);
      a[0] += v0.x; a[1] += v0.y; a[2] += v0.z; a[3] += v0.w;
      a[4] += v1.x; a[5] += v1.y; a[6] += v1.z; a[7] += v1.w;
      cnt += 1.f;
    }
  }
  float inv = 1.f / fmaxf(cnt, 1.f);
  const float* hx = Hf + (size_t)node * 2048 + c;
#pragma unroll
  for (int j = 0; j < 8; ++j) {
    float av = a[j] * inv, xv = hx[j];
    u16 ah = f2bf_u(av), xh = f2bf_u(xv);
    u16 al = f2bf_u(av - bf2f_u(ah)), xl = f2bf_u(xv - bf2f_u(xh));
    row[c + j] = ah; row[2048 + c + j] = xh;
    row[4096 + c + j] = al; row[6144 + c + j] = xl;
    row[8192 + c + j] = ah; row[10240 + c + j] = xh;
  }
}

// partial-sum + bias kernels
__global__ void k_relu_bias_f32(const float* __restrict__ acc, const float* __restrict__ bias,
                                float* __restrict__ out, int N, int total, int nz, int zs) {
  int idx = blockIdx.x * 256 + threadIdx.x;
  if (idx >= total) return;
  float s = 0.f;
  for (int z = 0; z < nz; ++z) s += acc[(size_t)z * zs + idx];
  out[idx] = fmaxf(s + bias[idx % N], 0.f);
}
__global__ void k_bias_bf16(const float* __restrict__ acc, const float* __restrict__ bias,
                            u16* __restrict__ out, int N, int total, int nz, int zs) {
  int idx = blockIdx.x * 256 + threadIdx.x;
  if (idx >= total) return;
  float s = 0.f;
  for (int z = 0; z < nz; ++z) s += acc[(size_t)z * zs + idx];
  out[idx] = f2bf_u(s + bias[idx % N]);
}

__global__ void k_cvt_bf16(const float* __restrict__ src, u16* __restrict__ dst, int n4) {
  int idx = blockIdx.x * 256 + threadIdx.x;
  if (idx >= n4) return;
  float4 v = *(const float4*)(src + ((size_t)idx << 2));
  ushort4 o;
  o.x = f2bf_u(v.x); o.y = f2bf_u(v.y); o.z = f2bf_u(v.z); o.w = f2bf_u(v.w);
  *(ushort4*)(dst + ((size_t)idx << 2)) = o;
}

// H1[r][c<1000] = relu(F[a(r)][c] + G[115+o(r)][c] + bp1[c]); pad 0 to 1024.
// T1[rt][c<800] = relu(I1[rt][c] + bi1[c]); pad 0 to 832.
__global__ void k_buildH1T1(const float* __restrict__ Facc,
                            const int* __restrict__ t_attr, const int* __restrict__ obj,
                            const int* __restrict__ negat, const float* __restrict__ bp1,
                            const float* __restrict__ bi1,
                            u16* __restrict__ H1, u16* __restrict__ T1) {
  int idx = blockIdx.x * 256 + threadIdx.x;
  if (idx >= 29696 * 128) return;
  int r = idx >> 7, ch = idx & 127, c = ch << 3;
  if (r < 29440) {
    u16* dst = H1 + ((size_t)r << 10) + c;
    if (c >= 1000) { ushort4 z = {0,0,0,0}; *(ushort4*)dst = z; *(ushort4*)(dst + 4) = z; return; }
    int a, o;
    if (r < 256) { a = t_attr[r]; o = obj[r]; }
    else { int rr = r - 256; a = negat[rr]; o = obj[rr / 114]; }
    const float* Fa = Facc + (size_t)a * 4096 + c;
    const float* Go = Facc + (size_t)(115 + o) * 4096 + 1024 + c;
    const float* Bp = bp1 + c;
    ushort4 o0, o1;
    float4 f0 = *(const float4*)Fa, f1 = *(const float4*)(Fa + 4);
    float4 g0 = *(const float4*)Go, g1 = *(const float4*)(Go + 4);
    float4 b0 = *(const float4*)Bp, b1 = *(const float4*)(Bp + 4);
    o0.x = f2bf_u(fmaxf(f0.x + g0.x + b0.x, 0.f));
    o0.y = f2bf_u(fmaxf(f0.y + g0.y + b0.y, 0.f));
    o0.z = f2bf_u(fmaxf(f0.z + g0.z + b0.z, 0.f));
    o0.w = f2bf_u(fmaxf(f0.w + g0.w + b0.w, 0.f));
    o1.x = f2bf_u(fmaxf(f1.x + g1.x + b1.x, 0.f));
    o1.y = f2bf_u(fmaxf(f1.y + g1.y + b1.y, 0.f));
    o1.z = f2bf_u(fmaxf(f1.z + g1.z + b1.z, 0.f));
    o1.w = f2bf_u(fmaxf(f1.w + g1.w + b1.w, 0.f));
    *(ushort4*)dst = o0; *(ushort4*)(dst + 4) = o1;
  } else {
    int rt = r - 29440;
    if (ch >= 104) return;
    u16* dst = T1 + (size_t)rt * 832 + c;
    if (c >= 800) { ushort4 z = {0,0,0,0}; *(ushort4*)dst = z; *(ushort4*)(dst + 4) = z; return; }
    const float* I1 = Facc + (size_t)(384 + rt) * 4096 + 2048 + c;
    const float* Bi = bi1 + c;
    float4 f0 = *(const float4*)I1, f1 = *(const float4*)(I1 + 4);
    float4 b0 = *(const float4*)Bi, b1 = *(const float4*)(Bi + 4);
    ushort4 o0, o1;
    o0.x = f2bf_u(fmaxf(f0.x + b0.x, 0.f)); o0.y = f2bf_u(fmaxf(f0.y + b0.y, 0.f));
    o0.z = f2bf_u(fmaxf(f0.z + b0.z, 0.f)); o0.w = f2bf_u(fmaxf(f0.w + b0.w, 0.f));
    o1.x = f2bf_u(fmaxf(f1.x + b1.x, 0.f)); o1.y = f2bf_u(fmaxf(f1.y + b1.y, 0.f));
    o1.z = f2bf_u(fmaxf(f1.z + b1.z, 0.f)); o1.w = f2bf_u(fmaxf(f1.w + b1.w, 0.f));
    *(ushort4*)dst = o0; *(ushort4*)(dst + 4) = o1;
  }
}

// reduce 14 partials -> rs = rsqrt(sum)
__global__ void k_rs(const float* __restrict__ part, int nrows, float* __restrict__ rs) {
  int idx = blockIdx.x * 256 + threadIdx.x;
  if (idx >= nrows) return;
  float s = 0.f;
#pragma unroll
  for (int i = 0; i < 14; ++i) s += part[(size_t)i * nrows + idx];
  rs[idx] = rsqrtf(fmaxf(s, 1e-24f));
}

// scale the three f32 output regions; rs computed inline from 14 partials
__global__ void k_norm3(float* __restrict__ cTheta, float* __restrict__ cNeg,
                        float* __restrict__ cTgt, const float* __restrict__ part,
                        int nrows) {
  int r = blockIdx.x;
  float ssum = 0.f;
#pragma unroll
  for (int i = 0; i < 14; ++i) ssum += part[(size_t)i * nrows + r];
  float s = rsqrtf(fmaxf(ssum, 1e-24f));
  float* row = (r < 256) ? cTheta + (size_t)r * 800
             : (r < 29440) ? cNeg + (size_t)(r - 256) * 800
                           : cTgt + (size_t)(r - 29440) * 800;
  int c = threadIdx.x;
  if (c < 200) {
    float4 v = *(float4*)(row + (c << 2));
    v.x *= s; v.y *= s; v.z *= s; v.w *= s;
    *(float4*)(row + (c << 2)) = v;
  }
}

// ---------------------------------------------------------------------------
extern "C" void kernel_launch(void* const* d_in, const int* in_sizes, int n_in,
                              void* d_out, int out_size, void* d_ws, size_t ws_size,
                              hipStream_t stream) {
  const float* nodes = (const float*)d_in[0];
  const float* s_img = (const float*)d_in[1];
  const float* t_img = (const float*)d_in[2];
  const float* Wl1 = (const float*)d_in[3];
  const float* Wr1 = (const float*)d_in[4];
  const float* b1  = (const float*)d_in[5];
  const float* Wl2 = (const float*)d_in[6];
  const float* Wr2 = (const float*)d_in[7];
  const float* b2  = (const float*)d_in[8];
  const float* Wp1 = (const float*)d_in[9];
  const float* bp1 = (const float*)d_in[10];
  const float* Wp2 = (const float*)d_in[11];
  const float* bp2 = (const float*)d_in[12];
  const float* Wi1 = (const float*)d_in[13];
  const float* bi1 = (const float*)d_in[14];
  const float* Wi2 = (const float*)d_in[15];
  const float* bi2 = (const float*)d_in[16];
  const float* Wi3 = (const float*)d_in[17];
  const float* bi3 = (const float*)d_in[18];
  const float* Wc1 = (const float*)d_in[19];
  const float* bc1 = (const float*)d_in[20];
  const float* Wc2 = (const float*)d_in[21];
  const float* bc2 = (const float*)d_in[22];
  const float* Wc3 = (const float*)d_in[23];
  const float* bc3 = (const float*)d_in[24];
  const int* e_src = (const int*)d_in[25];
  const int* e_dst = (const int*)d_in[26];
  const int* t_attr = (const int*)d_in[27];
  const int* obj    = (const int*)d_in[28];
  const int* negat  = (const int*)d_in[29];
  (void)in_sizes; (void)n_in; (void)out_size; (void)ws_size;

  float* out = (float*)d_out;
  float* cTheta = out;
  float* cTgt = out + 204800;
  float* cNeg = out + 409600;

  char* p = (char*)d_ws;
  auto alloc = [&](size_t bytes) -> void* {
    char* r = p; p += (bytes + 255) & ~(size_t)255; return (void*)r;
  };
  u16* W1t   = (u16*)alloc(2048ull * 3072 * 2);
  u16* W2t   = (u16*)alloc(512ull * 12288 * 2);
  u16* Wp2t  = (u16*)alloc(1024ull * 1024 * 2);
  u16* Wc1bt = (u16*)alloc(1024ull * 832 * 2);
  u16* Wc2t  = (u16*)alloc(1024ull * 896 * 2);
  u16* Wc3t  = (u16*)alloc(1024ull * 1024 * 2);
  u16* Wi2t  = (u16*)alloc(1024ull * 832 * 2);
  u16* Wi3t  = (u16*)alloc(1024ull * 1024 * 2);
  u16* Wcat  = (u16*)alloc(4096ull * 512 * 2);
  u16* Agp   = (u16*)alloc(384ull * 3072 * 2);
  float* Hacc = (float*)alloc(4ull * 384 * 2048 * 4);
  float* Hf   = (float*)alloc(384ull * 2048 * 4);
  u16* A2p   = (u16*)alloc(384ull * 12288 * 2);
  float* Zacc = (float*)alloc(8ull * 384 * 512 * 4);
  u16* A_cat = (u16*)alloc(896ull * 512 * 2);
  float* Facc = (float*)alloc(896ull * 4096 * 4);
  u16* T1    = (u16*)alloc(256ull * 832 * 2);
  u16* T2    = (u16*)alloc(256ull * 1024 * 2);
  float* rsqP16 = (float*)alloc(16ull * 29440 * 4);
  float* rsqC16 = (float*)alloc(16ull * 29696 * 4);
  float* rsP = (float*)alloc(29440ull * 4);
  u16* H1 = (u16*)alloc(29440ull * 1024 * 2);
  u16* X  = (u16*)alloc(29440ull * 832 * 2);
  u16* H3 = (u16*)alloc(29440ull * 1024 * 2);
  u16* H2 = H1;   // [29440][896] aliases H1 (dead after D2)

  dim3 tb(16, 16);
  k_pack_split<<<dim3(192, 128), tb, 0, stream>>>(Wl1, Wr1, 512, 1024, 2048, W1t, 3072);
  k_pack_split<<<dim3(768, 32), tb, 0, stream>>>(Wl2, Wr2, 2048, 4096, 512, W2t, 12288);
  {
    PJobs J;
    J.j[0] = {Wp2, Wp2t, 1000, 800, 1024, 1024, 1024};
    J.j[1] = {Wc1 + 512 * 800, Wc1bt, 800, 800, 832, 1024, 832};
    J.j[2] = {Wc2, Wc2t, 800, 1000, 896, 1024, 896};
    J.j[3] = {Wc3, Wc3t, 1000, 800, 1024, 1024, 1024};
    J.j[4] = {Wi2, Wi2t, 800, 1000, 832, 1024, 832};
    J.j[5] = {Wi3, Wi3t, 1000, 800, 1024, 1024, 1024};
    J.j[6] = {Wp1, Wcat, 512, 1000, 512, 1024, 512};
    J.j[7] = {Wp1 + 512 * 1000, Wcat + 1024 * 512, 512, 1000, 512, 1024, 512};
    J.j[8] = {Wi1, Wcat + 2048 * 512, 512, 800, 512, 1024, 512};
    J.j[9] = {Wc1, Wcat + 3072 * 512, 512, 800, 512, 1024, 512};
    k_pack10<<<dim3(64, 64, 10), tb, 0, stream>>>(J);
  }

  // SAGE
  k_aggpack1<<<dim3(384), 256, 0, stream>>>(e_src, e_dst, nodes, Agp);
  gemm_atom<0><<<dim3(16, 3, 4), 256, 0, stream>>>(Agp, 3072, W1t, 3072, 2048, 96, 24,
                                                   Hacc, 2048, 384 * 2048);
  k_relu_bias_f32<<<dim3(384 * 2048 / 256), 256, 0, stream>>>(Hacc, b1, Hf, 2048,
                                                              384 * 2048, 4, 384 * 2048);
  k_aggpack2<<<dim3(384), 256, 0, stream>>>(e_src, e_dst, Hf, A2p);
  gemm_atom<0><<<dim3(4, 3, 8), 256, 0, stream>>>(A2p, 12288, W2t, 12288, 512, 384, 48,
                                                  Zacc, 512, 384 * 512);
  k_bias_bf16<<<dim3(384 * 512 / 256), 256, 0, stream>>>(Zacc, b2, A_cat, 512,
                                                         384 * 512, 8, 384 * 512);
  k_cvt_bf16<<<dim3(128), 256, 0, stream>>>(t_img, A_cat + 384 * 512, 256 * 512 / 4);
  k_cvt_bf16<<<dim3(128), 256, 0, stream>>>(s_img, A_cat + 640 * 512, 256 * 512 / 4);

  // mega: [z | pad | t_img | s_img] @ [Wp1_top || Wp1_bot || Wi1 || Wc1_top]
  gemm_atom<1><<<dim3(32, 7, 1), 256, 0, stream>>>(A_cat, 512, Wcat, 512, 4096, 16, 16,
                                                   Facc, 4096, 0);
  k_buildH1T1<<<dim3(29696 * 128 / 256), 256, 0, stream>>>(Facc, t_attr, obj, negat,
                                                           bp1, bi1, H1, T1);

  // D2: pair_fc L2 -> X + rowsq partials  (K=1024 -> nK=32), grid 230x7
  {
    Panel s0{H1, 1024, Wp2t, 1024, bp2, 800, 832, 32, X, 832, nullptr, nullptr, 7, 0};
    gemm128<1><<<dim3(1610), 256, 0, stream>>>(s0, s0, 1 << 30, rsqP16, 29440,
                                               nullptr, nullptr, nullptr);
  }
  k_rs<<<dim3(115), 256, 0, stream>>>(rsqP16, 29440, rsP);

  // D3: compo L1 (K=832, rs+S, N=896, 230x7) + img L2 (N=1024, 2x8)
  {
    Panel s0{X, 832, Wc1bt, 832, bc1, 800, 896, 26, H2, 896, rsP,
             Facc + 640 * 4096 + 3072, 7, 0};
    Panel s1{T1, 832, Wi2t, 832, bi2, 1000, 1024, 26, T2, 1024, nullptr, nullptr, 8, 29440};
    gemm128<0><<<dim3(1626), 256, 0, stream>>>(s0, s1, 1610, nullptr, 0,
                                               nullptr, nullptr, nullptr);
  }
  // D4: compo L2 (K=896 -> nK=28, N=1024, 230x8)
  {
    Panel s0{H2, 896, Wc2t, 896, bc2, 1000, 1024, 28, H3, 1024, nullptr, nullptr, 8, 0};
    gemm128<0><<<dim3(1840), 256, 0, stream>>>(s0, s0, 1 << 30, nullptr, 0,
                                               nullptr, nullptr, nullptr);
  }
  // D5: compo L3 (theta+neg, 230x7) + img L3 (targets, 2x7), f32 out + rowsq
  {
    Panel s0{H3, 1024, Wc3t, 1024, bc3, 800, 800, 32, nullptr, 800, nullptr, nullptr, 7, 0};
    Panel s1{T2, 1024, Wi3t, 1024, bi3, 800, 800, 32, nullptr, 800, nullptr, nullptr, 7, 29440};
    gemm128<3><<<dim3(1624), 256, 0, stream>>>(s0, s1, 1610, rsqC16, 29696,
                                               cTheta, cNeg, cTgt);
  }
  k_norm3<<<dim3(29696), 256, 0, stream>>>(cTheta, cNeg, cTgt, rsqC16, 29696);
}

// Round 12
// 705.156 us; speedup vs baseline: 1.1327x; 1.1327x over previous
//
#include <hip/hip_runtime.h>

// ---------------------------------------------------------------------------
// GAE_IR_79499844649397. Atomic-free pipeline.
// Big GEMMs: R10 structure (best measured): 128x128 tile, 4 waves, BK=32,
// LDS 32KB dbuf + vmcnt(4), slot-XOR swizzle, __launch_bounds__(256,4),
// 1-D grid + XCD chunked swizzle. SAGE GEMMs: deeper split-K (z=8/16).
// ---------------------------------------------------------------------------

typedef unsigned short u16;
typedef __bf16 bf16x8 __attribute__((ext_vector_type(8)));
typedef float f32x4 __attribute__((ext_vector_type(4)));

__device__ inline u16 f2bf_u(float f) {
  union { float f; unsigned u; } a; a.f = f;
  unsigned u = a.u + 0x7fffu + ((a.u >> 16) & 1u);   // RNE
  return (u16)(u >> 16);
}
__device__ inline float bf2f_u(u16 h) {
  union { unsigned u; float f; } a; a.u = ((unsigned)h) << 16; return a.f;
}

#define GLOAD16(gptr, lptr)                                                   \
  __builtin_amdgcn_global_load_lds(                                           \
      (__attribute__((address_space(1))) void*)(gptr),                        \
      (__attribute__((address_space(3))) void*)(lptr), 16, 0, 0)

#define BAR  __builtin_amdgcn_s_barrier()
#define LGKM0 asm volatile("s_waitcnt lgkmcnt(0)" ::: "memory")
#define VMC4 asm volatile("s_waitcnt vmcnt(4)" ::: "memory")
#define VMC0 asm volatile("s_waitcnt vmcnt(0)" ::: "memory")

struct Panel {
  const u16* A; int lda;
  const u16* B; int ldb;
  const float* bias; int biasN;
  int N; int nK;               // nK in units of 32
  void* out; int ldc;
  const float* rsVec;          // optional per-row scale (pre-rsqrt'd)
  const float* addS;           // optional gathered row-add (f32, ld 4096)
  int gx;                      // col-blocks (N tiles of 128)
  int rowG0;                   // global row offset of this panel
};

// MODE 0: bf16 out, v = relu(acc*rs + bias + S[b])
// MODE 1: bf16 out + bias, + rowsq partials
// MODE 3: f32 out + bias, 3-range remap + rowsq partials
template <int MODE>
__global__ __launch_bounds__(256, 4) void gemm128(
    Panel p0, Panel p1, int c0,
    float* __restrict__ rsPart, int rsLd,
    float* __restrict__ cTheta, float* __restrict__ cNeg, float* __restrict__ cTgt) {
  __shared__ u16 As[2][4096];   // [128][32] x2
  __shared__ u16 Bs[2][4096];

  // chunked-bijective XCD swizzle (1-D grid)
  const int nwg = gridDim.x;
  const int orig = blockIdx.x;
  const int q = nwg >> 3, r = nwg & 7, xcd = orig & 7;
  const int basewg = (xcd < r) ? xcd * (q + 1) : r * (q + 1) + (xcd - r) * q;
  const int wg = basewg + (orig >> 3);

  Panel P; int pby, pbx;
  if (wg < c0) { P = p0; pby = wg / p0.gx; pbx = wg - pby * p0.gx; }
  else { P = p1; const int w2 = wg - c0; pby = w2 / p1.gx; pbx = w2 - pby * p1.gx; }
  const int m0 = pby << 7, n0 = pbx << 7;

  const int tid = threadIdx.x;
  const int wave = tid >> 6, lane = tid & 63;
  const int lr = lane & 15, lg = lane >> 4;
  const int wr = wave >> 1, wc = wave & 1;

  f32x4 acc[4][4] = {};

  // staging with slot-XOR swizzle: LDS[row][sc] = G[row][sc ^ ((row>>1)&3)]
  const int r0 = tid >> 2, sc0 = tid & 3;
  const size_t aOff  = (size_t)(m0 + r0) * P.lda + ((sc0 ^ ((r0 >> 1) & 3)) << 3);
  const size_t aOff1 = (size_t)(m0 + r0 + 64) * P.lda + ((sc0 ^ (((r0 + 64) >> 1) & 3)) << 3);
  const size_t bOff  = (size_t)(n0 + r0) * P.ldb + ((sc0 ^ ((r0 >> 1) & 3)) << 3);
  const size_t bOff1 = (size_t)(n0 + r0 + 64) * P.ldb + ((sc0 ^ (((r0 + 64) >> 1) & 3)) << 3);
  const int lL = (r0 * 4 + sc0) << 4;   // byte offset within buffer (linear dest)

  auto stage = [&](int kt, int b) {
    const int k0 = kt << 5;
    GLOAD16(P.A + aOff + k0, (char*)As[b] + lL);
    GLOAD16(P.A + aOff1 + k0, (char*)As[b] + lL + 4096);
    GLOAD16(P.B + bOff + k0, (char*)Bs[b] + lL);
    GLOAD16(P.B + bOff1 + k0, (char*)Bs[b] + lL + 4096);
  };

  const int nK = P.nK;
  stage(0, 0);
  for (int kt = 0; kt < nK; ++kt) {
    const int cb = kt & 1;
    if (kt + 1 < nK) { stage(kt + 1, cb ^ 1); VMC4; }
    else { VMC0; }
    BAR;

    bf16x8 af[4], bv[4];
#pragma unroll
    for (int m = 0; m < 4; ++m) {
      const int row = (wr << 6) + (m << 4) + lr;
      af[m] = *(const bf16x8*)(&As[cb][row * 32 + ((lg ^ ((row >> 1) & 3)) << 3)]);
    }
#pragma unroll
    for (int n = 0; n < 4; ++n) {
      const int row = (wc << 6) + (n << 4) + lr;
      bv[n] = *(const bf16x8*)(&Bs[cb][row * 32 + ((lg ^ ((row >> 1) & 3)) << 3)]);
    }
#pragma unroll
    for (int m = 0; m < 4; ++m)
#pragma unroll
      for (int n = 0; n < 4; ++n)
        acc[m][n] = __builtin_amdgcn_mfma_f32_16x16x32_bf16(af[m], bv[n], acc[m][n], 0, 0, 0);

    LGKM0;
    BAR;
  }

  const int gcb = n0 + (wc << 6);
  const int grb = m0 + (wr << 6) + (lg << 2);
#pragma unroll
  for (int m = 0; m < 4; ++m) {
#pragma unroll
    for (int rr = 0; rr < 4; ++rr) {
      const int grow = grb + (m << 4) + rr;
      const int growG = P.rowG0 + grow;
      float ss = 0.f;
      float rs = 1.f;
      const float* Sp = nullptr;
      if (MODE == 0) {
        if (P.rsVec) rs = P.rsVec[growG];
        if (P.addS) {
          int bv2 = (growG < 256) ? growG : (growG - 256) / 114;
          Sp = P.addS + (size_t)bv2 * 4096;
        }
      }
#pragma unroll
      for (int n = 0; n < 4; ++n) {
        const int gc = gcb + (n << 4) + lr;
        if (gc >= P.N) continue;
        float v = acc[m][n][rr];
        if (MODE == 0) {
          v *= rs;
          if (gc < P.biasN) v += P.bias[gc];
          if (Sp) v += Sp[gc];
          v = fmaxf(v, 0.f);
          ((u16*)P.out)[(size_t)grow * P.ldc + gc] = f2bf_u(v);
        } else if (MODE == 1) {
          if (gc < P.biasN) v += P.bias[gc];
          ((u16*)P.out)[(size_t)grow * P.ldc + gc] = f2bf_u(v);
          ss += v * v;
        } else {
          if (gc < P.biasN) v += P.bias[gc];
          float* op = (growG < 256) ? cTheta + (size_t)growG * 800
                    : (growG < 29440) ? cNeg + (size_t)(growG - 256) * 800
                                      : cTgt + (size_t)(growG - 29440) * 800;
          op[gc] = v;
          ss += v * v;
        }
      }
      if (MODE == 1 || MODE == 3) {
        ss += __shfl_xor(ss, 1); ss += __shfl_xor(ss, 2);
        ss += __shfl_xor(ss, 4); ss += __shfl_xor(ss, 8);
        if (lr == 0) rsPart[(size_t)((pbx << 1) + wc) * rsLd + growG] = ss;
      }
    }
  }
}

// ---------------------------------------------------------------------------
// Small-M GEMM: 128x128, BK=32. STORE=1 plain store; else z-partial store.
// ---------------------------------------------------------------------------
template <int STORE>
__global__ __launch_bounds__(256) void gemm_atom(
    const u16* __restrict__ A, int lda, const u16* __restrict__ Bt, int ldb,
    int N, int nK, int ktChunk, float* __restrict__ Cf, int ldc, int zStride) {
  __shared__ u16 As[2][4096];
  __shared__ u16 Bs[2][4096];
  const int tid = threadIdx.x;
  const int wave = tid >> 6, lane = tid & 63;
  const int lr = lane & 15, lg = lane >> 4;
  const int wr = wave >> 1, wc = wave & 1;
  const int m0 = blockIdx.y << 7, n0 = blockIdx.x << 7;

  f32x4 acc[4][4] = {};

  const size_t aOff  = (size_t)(m0 + (tid >> 2)) * lda + ((tid & 3) << 3);
  const size_t aOff1 = aOff + (size_t)64 * lda;
  const size_t bOff  = (size_t)(n0 + (tid >> 2)) * ldb + ((tid & 3) << 3);
  const size_t bOff1 = bOff + (size_t)64 * ldb;

  const int kt0 = blockIdx.z * ktChunk;
  int ktEnd = kt0 + ktChunk; if (ktEnd > nK) ktEnd = nK;

  auto stage = [&](int kt, int b) {
    const int k0 = kt << 5;
    u16* Ad = &As[b][wave << 9];
    u16* Bd = &Bs[b][wave << 9];
    GLOAD16(A + aOff + k0, Ad);
    GLOAD16(A + aOff1 + k0, Ad + 2048);
    GLOAD16(Bt + bOff + k0, Bd);
    GLOAD16(Bt + bOff1 + k0, Bd + 2048);
  };

  if (kt0 < ktEnd) stage(kt0, 0);
  for (int kt = kt0; kt < ktEnd; ++kt) {
    const int cb = (kt - kt0) & 1;
    if (kt + 1 < ktEnd) {
      stage(kt + 1, cb ^ 1);
      VMC4;
    } else {
      VMC0;
    }
    BAR;
    asm volatile("" ::: "memory");

    bf16x8 af[4], bvv[4];
#pragma unroll
    for (int m = 0; m < 4; ++m)
      af[m] = *(const bf16x8*)(&As[cb][(((wr << 6) + (m << 4) + lr) << 5) + (lg << 3)]);
#pragma unroll
    for (int n = 0; n < 4; ++n)
      bvv[n] = *(const bf16x8*)(&Bs[cb][(((wc << 6) + (n << 4) + lr) << 5) + (lg << 3)]);
#pragma unroll
    for (int m = 0; m < 4; ++m)
#pragma unroll
      for (int n = 0; n < 4; ++n)
        acc[m][n] = __builtin_amdgcn_mfma_f32_16x16x32_bf16(af[m], bvv[n], acc[m][n], 0, 0, 0);

    asm volatile("s_waitcnt lgkmcnt(0)" ::: "memory");
    BAR;
    asm volatile("" ::: "memory");
  }

  float* out = STORE ? Cf : (Cf + (size_t)blockIdx.z * zStride);
  const int gcb = n0 + (wc << 6);
  const int grb = m0 + (wr << 6) + (lg << 2);
#pragma unroll
  for (int m = 0; m < 4; ++m)
#pragma unroll
    for (int rr = 0; rr < 4; ++rr) {
      const int grow = grb + (m << 4) + rr;
#pragma unroll
      for (int n = 0; n < 4; ++n) {
        const int gc = gcb + (n << 4) + lr;
        if (gc < N) out[(size_t)grow * ldc + gc] = acc[m][n][rr];
      }
    }
}

// --------------------------- weight packing --------------------------------
struct PJob { const float* src; u16* dst; int Ksrc, Nsrc, Kpad, Npad, ld; };
struct PJobs { PJob j[10]; };

__global__ void k_pack10(PJobs J) {
  PJob job = J.j[blockIdx.z];
  const int k0 = blockIdx.x * 16, n0 = blockIdx.y * 16;
  if (k0 >= job.Kpad || n0 >= job.Npad) return;
  __shared__ float t[16][17];
  const int tx = threadIdx.x, ty = threadIdx.y;
  const int km = k0 + ty, n = n0 + tx;
  float v = (km < job.Ksrc && n < job.Nsrc) ? job.src[(size_t)km * job.Nsrc + n] : 0.f;
  t[ty][tx] = v;
  __syncthreads();
  if (k0 + tx < job.Kpad && n0 + ty < job.Npad)
    job.dst[(size_t)(n0 + ty) * job.ld + k0 + tx] = f2bf_u(t[tx][ty]);
}

// Split-bf16 stacked pack: W[Ktot][Nsrc] = [srcA(splitK); srcB]; k blocks [hi,hi,lo].
__global__ void k_pack_split(const float* __restrict__ srcA, const float* __restrict__ srcB,
                             int splitK, int Ktot, int Nsrc,
                             u16* __restrict__ dst, int dstLd) {
  __shared__ float t[16][17];
  const int k0 = blockIdx.x * 16, n0 = blockIdx.y * 16;
  const int tx = threadIdx.x, ty = threadIdx.y;
  int kOut = k0 + ty;
  int blk = kOut / Ktot; int km = kOut - blk * Ktot;
  const int n = n0 + tx;
  float v = 0.f;
  if (n < Nsrc)
    v = (km < splitK) ? srcA[(size_t)km * Nsrc + n]
                      : srcB[(size_t)(km - splitK) * Nsrc + n];
  t[ty][tx] = v;
  __syncthreads();
  const int kw = k0 + tx;
  const int blkw = kw / Ktot;
  float x = t[tx][ty];
  u16 hb = f2bf_u(x);
  u16 o = (blkw == 2) ? f2bf_u(x - bf2f_u(hb)) : hb;
  dst[(size_t)(n0 + ty) * dstLd + kw] = o;
}

// ---------------- SAGE aggregation (atomic-free per-node scan) -------------
__global__ void k_aggpack1(const int* __restrict__ es, const int* __restrict__ ed,
                           const float* __restrict__ nodes, u16* __restrict__ Agp) {
  const int node = blockIdx.x;              // 0..383
  const int c = threadIdx.x * 2;
  u16* row = Agp + (size_t)node * 3072;
  if (node >= 360) {
#pragma unroll
    for (int b = 0; b < 3; ++b) { row[b * 1024 + c] = 0; row[b * 1024 + c + 1] = 0;
                                  row[b * 1024 + 512 + c] = 0; row[b * 1024 + 512 + c + 1] = 0; }
    return;
  }
  float a0 = 0.f, a1 = 0.f, cnt = 0.f;
  for (int e = 0; e < 1262; ++e) {
    if (ed[e] == node) {
      const float* xr = nodes + (size_t)es[e] * 512;
      a0 += xr[c]; a1 += xr[c + 1]; cnt += 1.f;
    }
  }
  float inv = 1.f / fmaxf(cnt, 1.f);
  a0 *= inv; a1 *= inv;
  float x0 = nodes[(size_t)node * 512 + c], x1 = nodes[(size_t)node * 512 + c + 1];
  u16 ah0 = f2bf_u(a0), ah1 = f2bf_u(a1);
  u16 al0 = f2bf_u(a0 - bf2f_u(ah0)), al1 = f2bf_u(a1 - bf2f_u(ah1));
  u16 xh0 = f2bf_u(x0), xh1 = f2bf_u(x1);
  u16 xl0 = f2bf_u(x0 - bf2f_u(xh0)), xl1 = f2bf_u(x1 - bf2f_u(xh1));
  row[c] = ah0; row[c + 1] = ah1; row[512 + c] = xh0; row[512 + c + 1] = xh1;
  row[1024 + c] = al0; row[1024 + c + 1] = al1; row[1536 + c] = xl0; row[1536 + c + 1] = xl1;
  row[2048 + c] = ah0; row[2048 + c + 1] = ah1; row[2560 + c] = xh0; row[2560 + c + 1] = xh1;
}

__global__ void k_aggpack2(const int* __restrict__ es, const int* __restrict__ ed,
                           const float* __restrict__ Hf, u16* __restrict__ A2p) {
  const int node = blockIdx.x;              // 0..383
  const int c = threadIdx.x * 8;
  u16* row = A2p + (size_t)node * 12288;
  if (node >= 360) {
#pragma unroll
    for (int b = 0; b < 3; ++b)
      for (int j = 0; j < 8; ++j) { row[b * 4096 + c + j] = 0; row[b * 4096 + 2048 + c + j] = 0; }
    return;
  }
  float a[8] = {}; float cnt = 0.f;
  for (int e = 0; e < 1262; ++e) {
    if (ed[e] == node) {
      const float* hr = Hf + (size_t)es[e] * 2048 + c;
      float4 v0 = *(const float4*)hr, v1 = *(const float4*)(hr + 4);
      a[0] += v0.x; a[1] += v0.y; a[2] += v0.z; a[3] += v0.w;
      a[4] += v1.x; a[5] += v1.y; a[6] += v1.z; a[7] += v1.w;
      cnt += 1.f;
    }
  }
  float inv = 1.f / fmaxf(cnt, 1.f);
  const float* hx = Hf + (size_t)node * 2048 + c;
#pragma unroll
  for (int j = 0; j < 8; ++j) {
    float av = a[j] * inv, xv = hx[j];
    u16 ah = f2bf_u(av), xh = f2bf_u(xv);
    u16 al = f2bf_u(av - bf2f_u(ah)), xl = f2bf_u(xv - bf2f_u(xh));
    row[c + j] = ah; row[2048 + c + j] = xh;
    row[4096 + c + j] = al; row[6144 + c + j] = xl;
    row[8192 + c + j] = ah; row[10240 + c + j] = xh;
  }
}

// partial-sum + bias kernels
__global__ void k_relu_bias_f32(const float* __restrict__ acc, const float* __restrict__ bias,
                                float* __restrict__ out, int N, int total, int nz, int zs) {
  int idx = blockIdx.x * 256 + threadIdx.x;
  if (idx >= total) return;
  float s = 0.f;
  for (int z = 0; z < nz; ++z) s += acc[(size_t)z * zs + idx];
  out[idx] = fmaxf(s + bias[idx % N], 0.f);
}
__global__ void k_bias_bf16(const float* __restrict__ acc, const float* __restrict__ bias,
                            u16* __restrict__ out, int N, int total, int nz, int zs) {
  int idx = blockIdx.x * 256 + threadIdx.x;
  if (idx >= total) return;
  float s = 0.f;
  for (int z = 0; z < nz; ++z) s += acc[(size_t)z * zs + idx];
  out[idx] = f2bf_u(s + bias[idx % N]);
}

// both t_img and s_img -> bf16 into A_cat (rows 384.. and 640..)
__global__ void k_cvt2(const float* __restrict__ t_img, const float* __restrict__ s_img,
                       u16* __restrict__ dstT, u16* __restrict__ dstS) {
  int idx = blockIdx.x * 256 + threadIdx.x;   // 2*32768 4-float chunks
  if (idx >= 65536) return;
  const float* src = (idx < 32768) ? t_img : s_img;
  u16* dst = (idx < 32768) ? dstT : dstS;
  int i = idx & 32767;
  float4 v = *(const float4*)(src + ((size_t)i << 2));
  ushort4 o;
  o.x = f2bf_u(v.x); o.y = f2bf_u(v.y); o.z = f2bf_u(v.z); o.w = f2bf_u(v.w);
  *(ushort4*)(dst + ((size_t)i << 2)) = o;
}

// H1[r][c<1000] = relu(F[a(r)][c] + G[115+o(r)][c] + bp1[c]); pad 0 to 1024.
// T1[rt][c<800] = relu(I1[rt][c] + bi1[c]); pad 0 to 832.
__global__ void k_buildH1T1(const float* __restrict__ Facc,
                            const int* __restrict__ t_attr, const int* __restrict__ obj,
                            const int* __restrict__ negat, const float* __restrict__ bp1,
                            const float* __restrict__ bi1,
                            u16* __restrict__ H1, u16* __restrict__ T1) {
  int idx = blockIdx.x * 256 + threadIdx.x;
  if (idx >= 29696 * 128) return;
  int r = idx >> 7, ch = idx & 127, c = ch << 3;
  if (r < 29440) {
    u16* dst = H1 + ((size_t)r << 10) + c;
    if (c >= 1000) { ushort4 z = {0,0,0,0}; *(ushort4*)dst = z; *(ushort4*)(dst + 4) = z; return; }
    int a, o;
    if (r < 256) { a = t_attr[r]; o = obj[r]; }
    else { int rr = r - 256; a = negat[rr]; o = obj[rr / 114]; }
    const float* Fa = Facc + (size_t)a * 4096 + c;
    const float* Go = Facc + (size_t)(115 + o) * 4096 + 1024 + c;
    const float* Bp = bp1 + c;
    ushort4 o0, o1;
    float4 f0 = *(const float4*)Fa, f1 = *(const float4*)(Fa + 4);
    float4 g0 = *(const float4*)Go, g1 = *(const float4*)(Go + 4);
    float4 b0 = *(const float4*)Bp, b1 = *(const float4*)(Bp + 4);
    o0.x = f2bf_u(fmaxf(f0.x + g0.x + b0.x, 0.f));
    o0.y = f2bf_u(fmaxf(f0.y + g0.y + b0.y, 0.f));
    o0.z = f2bf_u(fmaxf(f0.z + g0.z + b0.z, 0.f));
    o0.w = f2bf_u(fmaxf(f0.w + g0.w + b0.w, 0.f));
    o1.x = f2bf_u(fmaxf(f1.x + g1.x + b1.x, 0.f));
    o1.y = f2bf_u(fmaxf(f1.y + g1.y + b1.y, 0.f));
    o1.z = f2bf_u(fmaxf(f1.z + g1.z + b1.z, 0.f));
    o1.w = f2bf_u(fmaxf(f1.w + g1.w + b1.w, 0.f));
    *(ushort4*)dst = o0; *(ushort4*)(dst + 4) = o1;
  } else {
    int rt = r - 29440;
    if (ch >= 104) return;
    u16* dst = T1 + (size_t)rt * 832 + c;
    if (c >= 800) { ushort4 z = {0,0,0,0}; *(ushort4*)dst = z; *(ushort4*)(dst + 4) = z; return; }
    const float* I1 = Facc + (size_t)(384 + rt) * 4096 + 2048 + c;
    const float* Bi = bi1 + c;
    float4 f0 = *(const float4*)I1, f1 = *(const float4*)(I1 + 4);
    float4 b0 = *(const float4*)Bi, b1 = *(const float4*)(Bi + 4);
    ushort4 o0, o1;
    o0.x = f2bf_u(fmaxf(f0.x + b0.x, 0.f)); o0.y = f2bf_u(fmaxf(f0.y + b0.y, 0.f));
    o0.z = f2bf_u(fmaxf(f0.z + b0.z, 0.f)); o0.w = f2bf_u(fmaxf(f0.w + b0.w, 0.f));
    o1.x = f2bf_u(fmaxf(f1.x + b1.x, 0.f)); o1.y = f2bf_u(fmaxf(f1.y + b1.y, 0.f));
    o1.z = f2bf_u(fmaxf(f1.z + b1.z, 0.f)); o1.w = f2bf_u(fmaxf(f1.w + b1.w, 0.f));
    *(ushort4*)dst = o0; *(ushort4*)(dst + 4) = o1;
  }
}

// reduce 14 partials -> rs = rsqrt(sum)
__global__ void k_rs(const float* __restrict__ part, int nrows, float* __restrict__ rs) {
  int idx = blockIdx.x * 256 + threadIdx.x;
  if (idx >= nrows) return;
  float s = 0.f;
#pragma unroll
  for (int i = 0; i < 14; ++i) s += part[(size_t)i * nrows + idx];
  rs[idx] = rsqrtf(fmaxf(s, 1e-24f));
}

// scale the three f32 output regions; rs computed inline from 14 partials
__global__ void k_norm3(float* __restrict__ cTheta, float* __restrict__ cNeg,
                        float* __restrict__ cTgt, const float* __restrict__ part,
                        int nrows) {
  int r = blockIdx.x;
  float ssum = 0.f;
#pragma unroll
  for (int i = 0; i < 14; ++i) ssum += part[(size_t)i * nrows + r];
  float s = rsqrtf(fmaxf(ssum, 1e-24f));
  float* row = (r < 256) ? cTheta + (size_t)r * 800
             : (r < 29440) ? cNeg + (size_t)(r - 256) * 800
                           : cTgt + (size_t)(r - 29440) * 800;
  int c = threadIdx.x;
  if (c < 200) {
    float4 v = *(float4*)(row + (c << 2));
    v.x *= s; v.y *= s; v.z *= s; v.w *= s;
    *(float4*)(row + (c << 2)) = v;
  }
}

// ---------------------------------------------------------------------------
extern "C" void kernel_launch(void* const* d_in, const int* in_sizes, int n_in,
                              void* d_out, int out_size, void* d_ws, size_t ws_size,
                              hipStream_t stream) {
  const float* nodes = (const float*)d_in[0];
  const float* s_img = (const float*)d_in[1];
  const float* t_img = (const float*)d_in[2];
  const float* Wl1 = (const float*)d_in[3];
  const float* Wr1 = (const float*)d_in[4];
  const float* b1  = (const float*)d_in[5];
  const float* Wl2 = (const float*)d_in[6];
  const float* Wr2 = (const float*)d_in[7];
  const float* b2  = (const float*)d_in[8];
  const float* Wp1 = (const float*)d_in[9];
  const float* bp1 = (const float*)d_in[10];
  const float* Wp2 = (const float*)d_in[11];
  const float* bp2 = (const float*)d_in[12];
  const float* Wi1 = (const float*)d_in[13];
  const float* bi1 = (const float*)d_in[14];
  const float* Wi2 = (const float*)d_in[15];
  const float* bi2 = (const float*)d_in[16];
  const float* Wi3 = (const float*)d_in[17];
  const float* bi3 = (const float*)d_in[18];
  const float* Wc1 = (const float*)d_in[19];
  const float* bc1 = (const float*)d_in[20];
  const float* Wc2 = (const float*)d_in[21];
  const float* bc2 = (const float*)d_in[22];
  const float* Wc3 = (const float*)d_in[23];
  const float* bc3 = (const float*)d_in[24];
  const int* e_src = (const int*)d_in[25];
  const int* e_dst = (const int*)d_in[26];
  const int* t_attr = (const int*)d_in[27];
  const int* obj    = (const int*)d_in[28];
  const int* negat  = (const int*)d_in[29];
  (void)in_sizes; (void)n_in; (void)out_size; (void)ws_size;

  float* out = (float*)d_out;
  float* cTheta = out;
  float* cTgt = out + 204800;
  float* cNeg = out + 409600;

  char* p = (char*)d_ws;
  auto alloc = [&](size_t bytes) -> void* {
    char* r = p; p += (bytes + 255) & ~(size_t)255; return (void*)r;
  };
  u16* W1t   = (u16*)alloc(2048ull * 3072 * 2);
  u16* W2t   = (u16*)alloc(512ull * 12288 * 2);
  u16* Wp2t  = (u16*)alloc(1024ull * 1024 * 2);
  u16* Wc1bt = (u16*)alloc(1024ull * 832 * 2);
  u16* Wc2t  = (u16*)alloc(1024ull * 896 * 2);
  u16* Wc3t  = (u16*)alloc(1024ull * 1024 * 2);
  u16* Wi2t  = (u16*)alloc(1024ull * 832 * 2);
  u16* Wi3t  = (u16*)alloc(1024ull * 1024 * 2);
  u16* Wcat  = (u16*)alloc(4096ull * 512 * 2);
  u16* Agp   = (u16*)alloc(384ull * 3072 * 2);
  float* Hacc = (float*)alloc(8ull * 384 * 2048 * 4);
  float* Hf   = (float*)alloc(384ull * 2048 * 4);
  u16* A2p   = (u16*)alloc(384ull * 12288 * 2);
  float* Zacc = (float*)alloc(16ull * 384 * 512 * 4);
  u16* A_cat = (u16*)alloc(896ull * 512 * 2);
  float* Facc = (float*)alloc(896ull * 4096 * 4);
  u16* T1    = (u16*)alloc(256ull * 832 * 2);
  u16* T2    = (u16*)alloc(256ull * 1024 * 2);
  float* rsqP16 = (float*)alloc(16ull * 29440 * 4);
  float* rsqC16 = (float*)alloc(16ull * 29696 * 4);
  float* rsP = (float*)alloc(29440ull * 4);
  u16* H1 = (u16*)alloc(29440ull * 1024 * 2);
  u16* X  = (u16*)alloc(29440ull * 832 * 2);
  u16* H3 = (u16*)alloc(29440ull * 1024 * 2);
  u16* H2 = H1;   // [29440][896] aliases H1 (dead after D2)

  dim3 tb(16, 16);
  k_pack_split<<<dim3(192, 128), tb, 0, stream>>>(Wl1, Wr1, 512, 1024, 2048, W1t, 3072);
  k_pack_split<<<dim3(768, 32), tb, 0, stream>>>(Wl2, Wr2, 2048, 4096, 512, W2t, 12288);
  {
    PJobs J;
    J.j[0] = {Wp2, Wp2t, 1000, 800, 1024, 1024, 1024};
    J.j[1] = {Wc1 + 512 * 800, Wc1bt, 800, 800, 832, 1024, 832};
    J.j[2] = {Wc2, Wc2t, 800, 1000, 896, 1024, 896};
    J.j[3] = {Wc3, Wc3t, 1000, 800, 1024, 1024, 1024};
    J.j[4] = {Wi2, Wi2t, 800, 1000, 832, 1024, 832};
    J.j[5] = {Wi3, Wi3t, 1000, 800, 1024, 1024, 1024};
    J.j[6] = {Wp1, Wcat, 512, 1000, 512, 1024, 512};
    J.j[7] = {Wp1 + 512 * 1000, Wcat + 1024 * 512, 512, 1000, 512, 1024, 512};
    J.j[8] = {Wi1, Wcat + 2048 * 512, 512, 800, 512, 1024, 512};
    J.j[9] = {Wc1, Wcat + 3072 * 512, 512, 800, 512, 1024, 512};
    k_pack10<<<dim3(64, 64, 10), tb, 0, stream>>>(J);
  }

  // SAGE (deeper split-K: z=8 / z=16)
  k_aggpack1<<<dim3(384), 256, 0, stream>>>(e_src, e_dst, nodes, Agp);
  gemm_atom<0><<<dim3(16, 3, 8), 256, 0, stream>>>(Agp, 3072, W1t, 3072, 2048, 96, 12,
                                                   Hacc, 2048, 384 * 2048);
  k_relu_bias_f32<<<dim3(384 * 2048 / 256), 256, 0, stream>>>(Hacc, b1, Hf, 2048,
                                                              384 * 2048, 8, 384 * 2048);
  k_aggpack2<<<dim3(384), 256, 0, stream>>>(e_src, e_dst, Hf, A2p);
  gemm_atom<0><<<dim3(4, 3, 16), 256, 0, stream>>>(A2p, 12288, W2t, 12288, 512, 384, 24,
                                                   Zacc, 512, 384 * 512);
  k_bias_bf16<<<dim3(384 * 512 / 256), 256, 0, stream>>>(Zacc, b2, A_cat, 512,
                                                         384 * 512, 16, 384 * 512);
  k_cvt2<<<dim3(256), 256, 0, stream>>>(t_img, s_img, A_cat + 384 * 512, A_cat + 640 * 512);

  // mega: [z | pad | t_img | s_img] @ [Wp1_top || Wp1_bot || Wi1 || Wc1_top]
  gemm_atom<1><<<dim3(32, 7, 1), 256, 0, stream>>>(A_cat, 512, Wcat, 512, 4096, 16, 16,
                                                   Facc, 4096, 0);
  k_buildH1T1<<<dim3(29696 * 128 / 256), 256, 0, stream>>>(Facc, t_attr, obj, negat,
                                                           bp1, bi1, H1, T1);

  // D2: pair_fc L2 -> X + rowsq partials  (K=1024 -> nK=32), grid 230x7
  {
    Panel s0{H1, 1024, Wp2t, 1024, bp2, 800, 832, 32, X, 832, nullptr, nullptr, 7, 0};
    gemm128<1><<<dim3(1610), 256, 0, stream>>>(s0, s0, 1 << 30, rsqP16, 29440,
                                               nullptr, nullptr, nullptr);
  }
  k_rs<<<dim3(115), 256, 0, stream>>>(rsqP16, 29440, rsP);

  // D3: compo L1 (K=832, rs+S, N=896, 230x7) + img L2 (N=1024, 2x8)
  {
    Panel s0{X, 832, Wc1bt, 832, bc1, 800, 896, 26, H2, 896, rsP,
             Facc + 640 * 4096 + 3072, 7, 0};
    Panel s1{T1, 832, Wi2t, 832, bi2, 1000, 1024, 26, T2, 1024, nullptr, nullptr, 8, 29440};
    gemm128<0><<<dim3(1626), 256, 0, stream>>>(s0, s1, 1610, nullptr, 0,
                                               nullptr, nullptr, nullptr);
  }
  // D4: compo L2 (K=896 -> nK=28, N=1024, 230x8)
  {
    Panel s0{H2, 896, Wc2t, 896, bc2, 1000, 1024, 28, H3, 1024, nullptr, nullptr, 8, 0};
    gemm128<0><<<dim3(1840), 256, 0, stream>>>(s0, s0, 1 << 30, nullptr, 0,
                                               nullptr, nullptr, nullptr);
  }
  // D5: compo L3 (theta+neg, 230x7) + img L3 (targets, 2x7), f32 out + rowsq
  {
    Panel s0{H3, 1024, Wc3t, 1024, bc3, 800, 800, 32, nullptr, 800, nullptr, nullptr, 7, 0};
    Panel s1{T2, 1024, Wi3t, 1024, bi3, 800, 800, 32, nullptr, 800, nullptr, nullptr, 7, 29440};
    gemm128<3><<<dim3(1624), 256, 0, stream>>>(s0, s1, 1610, rsqC16, 29696,
                                               cTheta, cNeg, cTgt);
  }
  k_norm3<<<dim3(29696), 256, 0, stream>>>(cTheta, cNeg, cTgt, rsqC16, 29696);
}

// Round 13
// 705.076 us; speedup vs baseline: 1.1328x; 1.0001x over previous
//
#include <hip/hip_runtime.h>

// ---------------------------------------------------------------------------
// GAE_IR_79499844649397. Atomic-free pipeline.
// Big GEMMs: R10 structure: 128x128 tile, 4 waves, BK=32, LDS 32KB dbuf +
// vmcnt(4), slot-XOR swizzle, __launch_bounds__(256,4), XCD chunked swizzle.
// SAGE: split-K z=8/16. Prep (packs+agg1+cvt) merged into ONE launch.
// ---------------------------------------------------------------------------

typedef unsigned short u16;
typedef __bf16 bf16x8 __attribute__((ext_vector_type(8)));
typedef float f32x4 __attribute__((ext_vector_type(4)));

__device__ inline u16 f2bf_u(float f) {
  union { float f; unsigned u; } a; a.f = f;
  unsigned u = a.u + 0x7fffu + ((a.u >> 16) & 1u);   // RNE
  return (u16)(u >> 16);
}
__device__ inline float bf2f_u(u16 h) {
  union { unsigned u; float f; } a; a.u = ((unsigned)h) << 16; return a.f;
}

#define GLOAD16(gptr, lptr)                                                   \
  __builtin_amdgcn_global_load_lds(                                           \
      (__attribute__((address_space(1))) void*)(gptr),                        \
      (__attribute__((address_space(3))) void*)(lptr), 16, 0, 0)

#define BAR  __builtin_amdgcn_s_barrier()
#define LGKM0 asm volatile("s_waitcnt lgkmcnt(0)" ::: "memory")
#define VMC4 asm volatile("s_waitcnt vmcnt(4)" ::: "memory")
#define VMC0 asm volatile("s_waitcnt vmcnt(0)" ::: "memory")

struct Panel {
  const u16* A; int lda;
  const u16* B; int ldb;
  const float* bias; int biasN;
  int N; int nK;               // nK in units of 32
  void* out; int ldc;
  const float* rsVec;          // optional per-row scale (pre-rsqrt'd)
  const float* addS;           // optional gathered row-add (f32, ld 4096)
  int gx;                      // col-blocks (N tiles of 128)
  int rowG0;                   // global row offset of this panel
};

// MODE 0: bf16 out, v = relu(acc*rs + bias + S[b])
// MODE 1: bf16 out + bias, + rowsq partials
// MODE 3: f32 out + bias, 3-range remap + rowsq partials
template <int MODE>
__global__ __launch_bounds__(256, 4) void gemm128(
    Panel p0, Panel p1, int c0,
    float* __restrict__ rsPart, int rsLd,
    float* __restrict__ cTheta, float* __restrict__ cNeg, float* __restrict__ cTgt) {
  __shared__ u16 As[2][4096];   // [128][32] x2
  __shared__ u16 Bs[2][4096];

  // chunked-bijective XCD swizzle (1-D grid)
  const int nwg = gridDim.x;
  const int orig = blockIdx.x;
  const int q = nwg >> 3, r = nwg & 7, xcd = orig & 7;
  const int basewg = (xcd < r) ? xcd * (q + 1) : r * (q + 1) + (xcd - r) * q;
  const int wg = basewg + (orig >> 3);

  Panel P; int pby, pbx;
  if (wg < c0) { P = p0; pby = wg / p0.gx; pbx = wg - pby * p0.gx; }
  else { P = p1; const int w2 = wg - c0; pby = w2 / p1.gx; pbx = w2 - pby * p1.gx; }
  const int m0 = pby << 7, n0 = pbx << 7;

  const int tid = threadIdx.x;
  const int wave = tid >> 6, lane = tid & 63;
  const int lr = lane & 15, lg = lane >> 4;
  const int wr = wave >> 1, wc = wave & 1;

  f32x4 acc[4][4] = {};

  // staging with slot-XOR swizzle: LDS[row][sc] = G[row][sc ^ ((row>>1)&3)]
  const int r0 = tid >> 2, sc0 = tid & 3;
  const size_t aOff  = (size_t)(m0 + r0) * P.lda + ((sc0 ^ ((r0 >> 1) & 3)) << 3);
  const size_t aOff1 = (size_t)(m0 + r0 + 64) * P.lda + ((sc0 ^ (((r0 + 64) >> 1) & 3)) << 3);
  const size_t bOff  = (size_t)(n0 + r0) * P.ldb + ((sc0 ^ ((r0 >> 1) & 3)) << 3);
  const size_t bOff1 = (size_t)(n0 + r0 + 64) * P.ldb + ((sc0 ^ (((r0 + 64) >> 1) & 3)) << 3);
  const int lL = (r0 * 4 + sc0) << 4;   // byte offset within buffer (linear dest)

  auto stage = [&](int kt, int b) {
    const int k0 = kt << 5;
    GLOAD16(P.A + aOff + k0, (char*)As[b] + lL);
    GLOAD16(P.A + aOff1 + k0, (char*)As[b] + lL + 4096);
    GLOAD16(P.B + bOff + k0, (char*)Bs[b] + lL);
    GLOAD16(P.B + bOff1 + k0, (char*)Bs[b] + lL + 4096);
  };

  const int nK = P.nK;
  stage(0, 0);
  for (int kt = 0; kt < nK; ++kt) {
    const int cb = kt & 1;
    if (kt + 1 < nK) { stage(kt + 1, cb ^ 1); VMC4; }
    else { VMC0; }
    BAR;

    bf16x8 af[4], bv[4];
#pragma unroll
    for (int m = 0; m < 4; ++m) {
      const int row = (wr << 6) + (m << 4) + lr;
      af[m] = *(const bf16x8*)(&As[cb][row * 32 + ((lg ^ ((row >> 1) & 3)) << 3)]);
    }
#pragma unroll
    for (int n = 0; n < 4; ++n) {
      const int row = (wc << 6) + (n << 4) + lr;
      bv[n] = *(const bf16x8*)(&Bs[cb][row * 32 + ((lg ^ ((row >> 1) & 3)) << 3)]);
    }
#pragma unroll
    for (int m = 0; m < 4; ++m)
#pragma unroll
      for (int n = 0; n < 4; ++n)
        acc[m][n] = __builtin_amdgcn_mfma_f32_16x16x32_bf16(af[m], bv[n], acc[m][n], 0, 0, 0);

    LGKM0;
    BAR;
  }

  const int gcb = n0 + (wc << 6);
  const int grb = m0 + (wr << 6) + (lg << 2);
#pragma unroll
  for (int m = 0; m < 4; ++m) {
#pragma unroll
    for (int rr = 0; rr < 4; ++rr) {
      const int grow = grb + (m << 4) + rr;
      const int growG = P.rowG0 + grow;
      float ss = 0.f;
      float rs = 1.f;
      const float* Sp = nullptr;
      if (MODE == 0) {
        if (P.rsVec) rs = P.rsVec[growG];
        if (P.addS) {
          int bv2 = (growG < 256) ? growG : (growG - 256) / 114;
          Sp = P.addS + (size_t)bv2 * 4096;
        }
      }
#pragma unroll
      for (int n = 0; n < 4; ++n) {
        const int gc = gcb + (n << 4) + lr;
        if (gc >= P.N) continue;
        float v = acc[m][n][rr];
        if (MODE == 0) {
          v *= rs;
          if (gc < P.biasN) v += P.bias[gc];
          if (Sp) v += Sp[gc];
          v = fmaxf(v, 0.f);
          ((u16*)P.out)[(size_t)grow * P.ldc + gc] = f2bf_u(v);
        } else if (MODE == 1) {
          if (gc < P.biasN) v += P.bias[gc];
          ((u16*)P.out)[(size_t)grow * P.ldc + gc] = f2bf_u(v);
          ss += v * v;
        } else {
          if (gc < P.biasN) v += P.bias[gc];
          float* op = (growG < 256) ? cTheta + (size_t)growG * 800
                    : (growG < 29440) ? cNeg + (size_t)(growG - 256) * 800
                                      : cTgt + (size_t)(growG - 29440) * 800;
          op[gc] = v;
          ss += v * v;
        }
      }
      if (MODE == 1 || MODE == 3) {
        ss += __shfl_xor(ss, 1); ss += __shfl_xor(ss, 2);
        ss += __shfl_xor(ss, 4); ss += __shfl_xor(ss, 8);
        if (lr == 0) rsPart[(size_t)((pbx << 1) + wc) * rsLd + growG] = ss;
      }
    }
  }
}

// ---------------------------------------------------------------------------
// Small-M GEMM: 128x128, BK=32. STORE=1 plain store; else z-partial store.
// ---------------------------------------------------------------------------
template <int STORE>
__global__ __launch_bounds__(256) void gemm_atom(
    const u16* __restrict__ A, int lda, const u16* __restrict__ Bt, int ldb,
    int N, int nK, int ktChunk, float* __restrict__ Cf, int ldc, int zStride) {
  __shared__ u16 As[2][4096];
  __shared__ u16 Bs[2][4096];
  const int tid = threadIdx.x;
  const int wave = tid >> 6, lane = tid & 63;
  const int lr = lane & 15, lg = lane >> 4;
  const int wr = wave >> 1, wc = wave & 1;
  const int m0 = blockIdx.y << 7, n0 = blockIdx.x << 7;

  f32x4 acc[4][4] = {};

  const size_t aOff  = (size_t)(m0 + (tid >> 2)) * lda + ((tid & 3) << 3);
  const size_t aOff1 = aOff + (size_t)64 * lda;
  const size_t bOff  = (size_t)(n0 + (tid >> 2)) * ldb + ((tid & 3) << 3);
  const size_t bOff1 = bOff + (size_t)64 * ldb;

  const int kt0 = blockIdx.z * ktChunk;
  int ktEnd = kt0 + ktChunk; if (ktEnd > nK) ktEnd = nK;

  auto stage = [&](int kt, int b) {
    const int k0 = kt << 5;
    u16* Ad = &As[b][wave << 9];
    u16* Bd = &Bs[b][wave << 9];
    GLOAD16(A + aOff + k0, Ad);
    GLOAD16(A + aOff1 + k0, Ad + 2048);
    GLOAD16(Bt + bOff + k0, Bd);
    GLOAD16(Bt + bOff1 + k0, Bd + 2048);
  };

  if (kt0 < ktEnd) stage(kt0, 0);
  for (int kt = kt0; kt < ktEnd; ++kt) {
    const int cb = (kt - kt0) & 1;
    if (kt + 1 < ktEnd) {
      stage(kt + 1, cb ^ 1);
      VMC4;
    } else {
      VMC0;
    }
    BAR;
    asm volatile("" ::: "memory");

    bf16x8 af[4], bvv[4];
#pragma unroll
    for (int m = 0; m < 4; ++m)
      af[m] = *(const bf16x8*)(&As[cb][(((wr << 6) + (m << 4) + lr) << 5) + (lg << 3)]);
#pragma unroll
    for (int n = 0; n < 4; ++n)
      bvv[n] = *(const bf16x8*)(&Bs[cb][(((wc << 6) + (n << 4) + lr) << 5) + (lg << 3)]);
#pragma unroll
    for (int m = 0; m < 4; ++m)
#pragma unroll
      for (int n = 0; n < 4; ++n)
        acc[m][n] = __builtin_amdgcn_mfma_f32_16x16x32_bf16(af[m], bvv[n], acc[m][n], 0, 0, 0);

    asm volatile("s_waitcnt lgkmcnt(0)" ::: "memory");
    BAR;
    asm volatile("" ::: "memory");
  }

  float* out = STORE ? Cf : (Cf + (size_t)blockIdx.z * zStride);
  const int gcb = n0 + (wc << 6);
  const int grb = m0 + (wr << 6) + (lg << 2);
#pragma unroll
  for (int m = 0; m < 4; ++m)
#pragma unroll
    for (int rr = 0; rr < 4; ++rr) {
      const int grow = grb + (m << 4) + rr;
#pragma unroll
      for (int n = 0; n < 4; ++n) {
        const int gc = gcb + (n << 4) + lr;
        if (gc < N) out[(size_t)grow * ldc + gc] = acc[m][n][rr];
      }
    }
}

// --------------------------- merged prep kernel ----------------------------
struct PJob { const float* src; u16* dst; int Ksrc, Nsrc, Kpad, Npad, ld; };
struct PJobs { PJob j[10]; };

// seg0: pack_split Wl1/Wr1  (24576 blocks: bx<192, by<128)
// seg1: pack_split Wl2/Wr2  (24576 blocks: bx<768, by<32)
// seg2: pack10              (40960 blocks: z<10, 64x64)
// seg3: aggpack1            (384 blocks)
// seg4: cvt2 t_img/s_img    (256 blocks)
__global__ __launch_bounds__(256) void k_prep(
    const float* __restrict__ Wl1, const float* __restrict__ Wr1,
    const float* __restrict__ Wl2, const float* __restrict__ Wr2,
    PJobs J,
    const int* __restrict__ es, const int* __restrict__ ed,
    const float* __restrict__ nodes,
    const float* __restrict__ t_img, const float* __restrict__ s_img,
    u16* __restrict__ W1t, u16* __restrict__ W2t,
    u16* __restrict__ Agp, u16* __restrict__ dstT, u16* __restrict__ dstS) {
  __shared__ float t[16][17];
  int b = blockIdx.x;
  const int tid = threadIdx.x;
  const int tx = tid & 15, ty = tid >> 4;

  if (b < 24576) {                    // pack_split 1
    const int bx = b % 192, by = b / 192;
    const int k0 = bx * 16, n0 = by * 16;
    const int kOut = k0 + ty;
    const int km = kOut & 1023;
    const int n = n0 + tx;
    float v = (km < 512) ? Wl1[(size_t)km * 2048 + n]
                         : Wr1[(size_t)(km - 512) * 2048 + n];
    t[ty][tx] = v;
    __syncthreads();
    const int kw = k0 + tx;
    float x = t[tx][ty];
    u16 hb = f2bf_u(x);
    u16 o = ((kw >> 10) == 2) ? f2bf_u(x - bf2f_u(hb)) : hb;
    W1t[(size_t)(n0 + ty) * 3072 + kw] = o;
    return;
  }
  b -= 24576;
  if (b < 24576) {                    // pack_split 2
    const int bx = b % 768, by = b / 768;
    const int k0 = bx * 16, n0 = by * 16;
    const int kOut = k0 + ty;
    const int km = kOut & 4095;
    const int n = n0 + tx;
    float v = (km < 2048) ? Wl2[(size_t)km * 512 + n]
                          : Wr2[(size_t)(km - 2048) * 512 + n];
    t[ty][tx] = v;
    __syncthreads();
    const int kw = k0 + tx;
    float x = t[tx][ty];
    u16 hb = f2bf_u(x);
    u16 o = ((kw >> 12) == 2) ? f2bf_u(x - bf2f_u(hb)) : hb;
    W2t[(size_t)(n0 + ty) * 12288 + kw] = o;
    return;
  }
  b -= 24576;
  if (b < 40960) {                    // pack10
    const int z = b >> 12, rem = b & 4095;
    const int bx = rem & 63, by = rem >> 6;
    PJob job = J.j[z];
    const int k0 = bx * 16, n0 = by * 16;
    if (k0 >= job.Kpad || n0 >= job.Npad) return;
    const int km = k0 + ty, n = n0 + tx;
    float v = (km < job.Ksrc && n < job.Nsrc) ? job.src[(size_t)km * job.Nsrc + n] : 0.f;
    t[ty][tx] = v;
    __syncthreads();
    if (k0 + tx < job.Kpad && n0 + ty < job.Npad)
      job.dst[(size_t)(n0 + ty) * job.ld + k0 + tx] = f2bf_u(t[tx][ty]);
    return;
  }
  b -= 40960;
  if (b < 384) {                      // aggpack1
    const int node = b;
    const int c = tid * 2;
    u16* row = Agp + (size_t)node * 3072;
    if (node >= 360) {
#pragma unroll
      for (int bb = 0; bb < 3; ++bb) { row[bb * 1024 + c] = 0; row[bb * 1024 + c + 1] = 0;
                                       row[bb * 1024 + 512 + c] = 0; row[bb * 1024 + 512 + c + 1] = 0; }
      return;
    }
    float a0 = 0.f, a1 = 0.f, cnt = 0.f;
    for (int e = 0; e < 1262; ++e) {
      if (ed[e] == node) {
        const float* xr = nodes + (size_t)es[e] * 512;
        a0 += xr[c]; a1 += xr[c + 1]; cnt += 1.f;
      }
    }
    float inv = 1.f / fmaxf(cnt, 1.f);
    a0 *= inv; a1 *= inv;
    float x0 = nodes[(size_t)node * 512 + c], x1 = nodes[(size_t)node * 512 + c + 1];
    u16 ah0 = f2bf_u(a0), ah1 = f2bf_u(a1);
    u16 al0 = f2bf_u(a0 - bf2f_u(ah0)), al1 = f2bf_u(a1 - bf2f_u(ah1));
    u16 xh0 = f2bf_u(x0), xh1 = f2bf_u(x1);
    u16 xl0 = f2bf_u(x0 - bf2f_u(xh0)), xl1 = f2bf_u(x1 - bf2f_u(xh1));
    row[c] = ah0; row[c + 1] = ah1; row[512 + c] = xh0; row[512 + c + 1] = xh1;
    row[1024 + c] = al0; row[1024 + c + 1] = al1; row[1536 + c] = xl0; row[1536 + c + 1] = xl1;
    row[2048 + c] = ah0; row[2048 + c + 1] = ah1; row[2560 + c] = xh0; row[2560 + c + 1] = xh1;
    return;
  }
  b -= 384;
  {                                   // cvt2
    const int idx = b * 256 + tid;    // < 65536
    const float* src = (idx < 32768) ? t_img : s_img;
    u16* dst = (idx < 32768) ? dstT : dstS;
    const int i = idx & 32767;
    float4 v = *(const float4*)(src + ((size_t)i << 2));
    ushort4 o;
    o.x = f2bf_u(v.x); o.y = f2bf_u(v.y); o.z = f2bf_u(v.z); o.w = f2bf_u(v.w);
    *(ushort4*)(dst + ((size_t)i << 2)) = o;
  }
}

// ---------------- SAGE aggregation layer-2 (atomic-free scan) --------------
__global__ void k_aggpack2(const int* __restrict__ es, const int* __restrict__ ed,
                           const float* __restrict__ Hf, u16* __restrict__ A2p) {
  const int node = blockIdx.x;              // 0..383
  const int c = threadIdx.x * 8;
  u16* row = A2p + (size_t)node * 12288;
  if (node >= 360) {
#pragma unroll
    for (int b = 0; b < 3; ++b)
      for (int j = 0; j < 8; ++j) { row[b * 4096 + c + j] = 0; row[b * 4096 + 2048 + c + j] = 0; }
    return;
  }
  float a[8] = {}; float cnt = 0.f;
  for (int e = 0; e < 1262; ++e) {
    if (ed[e] == node) {
      const float* hr = Hf + (size_t)es[e] * 2048 + c;
      float4 v0 = *(const float4*)hr, v1 = *(const float4*)(hr + 4);
      a[0] += v0.x; a[1] += v0.y; a[2] += v0.z; a[3] += v0.w;
      a[4] += v1.x; a[5] += v1.y; a[6] += v1.z; a[7] += v1.w;
      cnt += 1.f;
    }
  }
  float inv = 1.f / fmaxf(cnt, 1.f);
  const float* hx = Hf + (size_t)node * 2048 + c;
#pragma unroll
  for (int j = 0; j < 8; ++j) {
    float av = a[j] * inv, xv = hx[j];
    u16 ah = f2bf_u(av), xh = f2bf_u(xv);
    u16 al = f2bf_u(av - bf2f_u(ah)), xl = f2bf_u(xv - bf2f_u(xh));
    row[c + j] = ah; row[2048 + c + j] = xh;
    row[4096 + c + j] = al; row[6144 + c + j] = xl;
    row[8192 + c + j] = ah; row[10240 + c + j] = xh;
  }
}

// partial-sum + bias kernels
__global__ void k_relu_bias_f32(const float* __restrict__ acc, const float* __restrict__ bias,
                                float* __restrict__ out, int N, int total, int nz, int zs) {
  int idx = blockIdx.x * 256 + threadIdx.x;
  if (idx >= total) return;
  float s = 0.f;
  for (int z = 0; z < nz; ++z) s += acc[(size_t)z * zs + idx];
  out[idx] = fmaxf(s + bias[idx % N], 0.f);
}
__global__ void k_bias_bf16(const float* __restrict__ acc, const float* __restrict__ bias,
                            u16* __restrict__ out, int N, int total, int nz, int zs) {
  int idx = blockIdx.x * 256 + threadIdx.x;
  if (idx >= total) return;
  float s = 0.f;
  for (int z = 0; z < nz; ++z) s += acc[(size_t)z * zs + idx];
  out[idx] = f2bf_u(s + bias[idx % N]);
}

// H1[r][c<1000] = relu(F[a(r)][c] + G[115+o(r)][c] + bp1[c]); pad 0 to 1024.
// T1[rt][c<800] = relu(I1[rt][c] + bi1[c]); pad 0 to 832.
__global__ void k_buildH1T1(const float* __restrict__ Facc,
                            const int* __restrict__ t_attr, const int* __restrict__ obj,
                            const int* __restrict__ negat, const float* __restrict__ bp1,
                            const float* __restrict__ bi1,
                            u16* __restrict__ H1, u16* __restrict__ T1) {
  int idx = blockIdx.x * 256 + threadIdx.x;
  if (idx >= 29696 * 128) return;
  int r = idx >> 7, ch = idx & 127, c = ch << 3;
  if (r < 29440) {
    u16* dst = H1 + ((size_t)r << 10) + c;
    if (c >= 1000) { ushort4 z = {0,0,0,0}; *(ushort4*)dst = z; *(ushort4*)(dst + 4) = z; return; }
    int a, o;
    if (r < 256) { a = t_attr[r]; o = obj[r]; }
    else { int rr = r - 256; a = negat[rr]; o = obj[rr / 114]; }
    const float* Fa = Facc + (size_t)a * 4096 + c;
    const float* Go = Facc + (size_t)(115 + o) * 4096 + 1024 + c;
    const float* Bp = bp1 + c;
    ushort4 o0, o1;
    float4 f0 = *(const float4*)Fa, f1 = *(const float4*)(Fa + 4);
    float4 g0 = *(const float4*)Go, g1 = *(const float4*)(Go + 4);
    float4 b0 = *(const float4*)Bp, b1 = *(const float4*)(Bp + 4);
    o0.x = f2bf_u(fmaxf(f0.x + g0.x + b0.x, 0.f));
    o0.y = f2bf_u(fmaxf(f0.y + g0.y + b0.y, 0.f));
    o0.z = f2bf_u(fmaxf(f0.z + g0.z + b0.z, 0.f));
    o0.w = f2bf_u(fmaxf(f0.w + g0.w + b0.w, 0.f));
    o1.x = f2bf_u(fmaxf(f1.x + g1.x + b1.x, 0.f));
    o1.y = f2bf_u(fmaxf(f1.y + g1.y + b1.y, 0.f));
    o1.z = f2bf_u(fmaxf(f1.z + g1.z + b1.z, 0.f));
    o1.w = f2bf_u(fmaxf(f1.w + g1.w + b1.w, 0.f));
    *(ushort4*)dst = o0; *(ushort4*)(dst + 4) = o1;
  } else {
    int rt = r - 29440;
    if (ch >= 104) return;
    u16* dst = T1 + (size_t)rt * 832 + c;
    if (c >= 800) { ushort4 z = {0,0,0,0}; *(ushort4*)dst = z; *(ushort4*)(dst + 4) = z; return; }
    const float* I1 = Facc + (size_t)(384 + rt) * 4096 + 2048 + c;
    const float* Bi = bi1 + c;
    float4 f0 = *(const float4*)I1, f1 = *(const float4*)(I1 + 4);
    float4 b0 = *(const float4*)Bi, b1 = *(const float4*)(Bi + 4);
    ushort4 o0, o1;
    o0.x = f2bf_u(fmaxf(f0.x + b0.x, 0.f)); o0.y = f2bf_u(fmaxf(f0.y + b0.y, 0.f));
    o0.z = f2bf_u(fmaxf(f0.z + b0.z, 0.f)); o0.w = f2bf_u(fmaxf(f0.w + b0.w, 0.f));
    o1.x = f2bf_u(fmaxf(f1.x + b1.x, 0.f)); o1.y = f2bf_u(fmaxf(f1.y + b1.y, 0.f));
    o1.z = f2bf_u(fmaxf(f1.z + b1.z, 0.f)); o1.w = f2bf_u(fmaxf(f1.w + b1.w, 0.f));
    *(ushort4*)dst = o0; *(ushort4*)(dst + 4) = o1;
  }
}

// reduce 14 partials -> rs = rsqrt(sum)
__global__ void k_rs(const float* __restrict__ part, int nrows, float* __restrict__ rs) {
  int idx = blockIdx.x * 256 + threadIdx.x;
  if (idx >= nrows) return;
  float s = 0.f;
#pragma unroll
  for (int i = 0; i < 14; ++i) s += part[(size_t)i * nrows + idx];
  rs[idx] = rsqrtf(fmaxf(s, 1e-24f));
}

// scale the three f32 output regions; rs computed inline from 14 partials
__global__ void k_norm3(float* __restrict__ cTheta, float* __restrict__ cNeg,
                        float* __restrict__ cTgt, const float* __restrict__ part,
                        int nrows) {
  int r = blockIdx.x;
  float ssum = 0.f;
#pragma unroll
  for (int i = 0; i < 14; ++i) ssum += part[(size_t)i * nrows + r];
  float s = rsqrtf(fmaxf(ssum, 1e-24f));
  float* row = (r < 256) ? cTheta + (size_t)r * 800
             : (r < 29440) ? cNeg + (size_t)(r - 256) * 800
                           : cTgt + (size_t)(r - 29440) * 800;
  int c = threadIdx.x;
  if (c < 200) {
    float4 v = *(float4*)(row + (c << 2));
    v.x *= s; v.y *= s; v.z *= s; v.w *= s;
    *(float4*)(row + (c << 2)) = v;
  }
}

// ---------------------------------------------------------------------------
extern "C" void kernel_launch(void* const* d_in, const int* in_sizes, int n_in,
                              void* d_out, int out_size, void* d_ws, size_t ws_size,
                              hipStream_t stream) {
  const float* nodes = (const float*)d_in[0];
  const float* s_img = (const float*)d_in[1];
  const float* t_img = (const float*)d_in[2];
  const float* Wl1 = (const float*)d_in[3];
  const float* Wr1 = (const float*)d_in[4];
  const float* b1  = (const float*)d_in[5];
  const float* Wl2 = (const float*)d_in[6];
  const float* Wr2 = (const float*)d_in[7];
  const float* b2  = (const float*)d_in[8];
  const float* Wp1 = (const float*)d_in[9];
  const float* bp1 = (const float*)d_in[10];
  const float* Wp2 = (const float*)d_in[11];
  const float* bp2 = (const float*)d_in[12];
  const float* Wi1 = (const float*)d_in[13];
  const float* bi1 = (const float*)d_in[14];
  const float* Wi2 = (const float*)d_in[15];
  const float* bi2 = (const float*)d_in[16];
  const float* Wi3 = (const float*)d_in[17];
  const float* bi3 = (const float*)d_in[18];
  const float* Wc1 = (const float*)d_in[19];
  const float* bc1 = (const float*)d_in[20];
  const float* Wc2 = (const float*)d_in[21];
  const float* bc2 = (const float*)d_in[22];
  const float* Wc3 = (const float*)d_in[23];
  const float* bc3 = (const float*)d_in[24];
  const int* e_src = (const int*)d_in[25];
  const int* e_dst = (const int*)d_in[26];
  const int* t_attr = (const int*)d_in[27];
  const int* obj    = (const int*)d_in[28];
  const int* negat  = (const int*)d_in[29];
  (void)in_sizes; (void)n_in; (void)out_size; (void)ws_size;

  float* out = (float*)d_out;
  float* cTheta = out;
  float* cTgt = out + 204800;
  float* cNeg = out + 409600;

  char* p = (char*)d_ws;
  auto alloc = [&](size_t bytes) -> void* {
    char* r = p; p += (bytes + 255) & ~(size_t)255; return (void*)r;
  };
  u16* W1t   = (u16*)alloc(2048ull * 3072 * 2);
  u16* W2t   = (u16*)alloc(512ull * 12288 * 2);
  u16* Wp2t  = (u16*)alloc(1024ull * 1024 * 2);
  u16* Wc1bt = (u16*)alloc(1024ull * 832 * 2);
  u16* Wc2t  = (u16*)alloc(1024ull * 896 * 2);
  u16* Wc3t  = (u16*)alloc(1024ull * 1024 * 2);
  u16* Wi2t  = (u16*)alloc(1024ull * 832 * 2);
  u16* Wi3t  = (u16*)alloc(1024ull * 1024 * 2);
  u16* Wcat  = (u16*)alloc(4096ull * 512 * 2);
  u16* Agp   = (u16*)alloc(384ull * 3072 * 2);
  float* Hacc = (float*)alloc(8ull * 384 * 2048 * 4);
  float* Hf   = (float*)alloc(384ull * 2048 * 4);
  u16* A2p   = (u16*)alloc(384ull * 12288 * 2);
  float* Zacc = (float*)alloc(16ull * 384 * 512 * 4);
  u16* A_cat = (u16*)alloc(896ull * 512 * 2);
  float* Facc = (float*)alloc(896ull * 4096 * 4);
  u16* T1    = (u16*)alloc(256ull * 832 * 2);
  u16* T2    = (u16*)alloc(256ull * 1024 * 2);
  float* rsqP16 = (float*)alloc(16ull * 29440 * 4);
  float* rsqC16 = (float*)alloc(16ull * 29696 * 4);
  float* rsP = (float*)alloc(29440ull * 4);
  u16* H1 = (u16*)alloc(29440ull * 1024 * 2);
  u16* X  = (u16*)alloc(29440ull * 832 * 2);
  u16* H3 = (u16*)alloc(29440ull * 1024 * 2);
  u16* H2 = H1;   // [29440][896] aliases H1 (dead after D2)

  // merged prep: weight packs + agg1 + img converts (one launch)
  {
    PJobs J;
    J.j[0] = {Wp2, Wp2t, 1000, 800, 1024, 1024, 1024};
    J.j[1] = {Wc1 + 512 * 800, Wc1bt, 800, 800, 832, 1024, 832};
    J.j[2] = {Wc2, Wc2t, 800, 1000, 896, 1024, 896};
    J.j[3] = {Wc3, Wc3t, 1000, 800, 1024, 1024, 1024};
    J.j[4] = {Wi2, Wi2t, 800, 1000, 832, 1024, 832};
    J.j[5] = {Wi3, Wi3t, 1000, 800, 1024, 1024, 1024};
    J.j[6] = {Wp1, Wcat, 512, 1000, 512, 1024, 512};
    J.j[7] = {Wp1 + 512 * 1000, Wcat + 1024 * 512, 512, 1000, 512, 1024, 512};
    J.j[8] = {Wi1, Wcat + 2048 * 512, 512, 800, 512, 1024, 512};
    J.j[9] = {Wc1, Wcat + 3072 * 512, 512, 800, 512, 1024, 512};
    k_prep<<<dim3(90752), 256, 0, stream>>>(
        Wl1, Wr1, Wl2, Wr2, J, e_src, e_dst, nodes, t_img, s_img,
        W1t, W2t, Agp, A_cat + 384 * 512, A_cat + 640 * 512);
  }

  // SAGE (split-K z=8 / z=16)
  gemm_atom<0><<<dim3(16, 3, 8), 256, 0, stream>>>(Agp, 3072, W1t, 3072, 2048, 96, 12,
                                                   Hacc, 2048, 384 * 2048);
  k_relu_bias_f32<<<dim3(384 * 2048 / 256), 256, 0, stream>>>(Hacc, b1, Hf, 2048,
                                                              384 * 2048, 8, 384 * 2048);
  k_aggpack2<<<dim3(384), 256, 0, stream>>>(e_src, e_dst, Hf, A2p);
  gemm_atom<0><<<dim3(4, 3, 16), 256, 0, stream>>>(A2p, 12288, W2t, 12288, 512, 384, 24,
                                                   Zacc, 512, 384 * 512);
  k_bias_bf16<<<dim3(384 * 512 / 256), 256, 0, stream>>>(Zacc, b2, A_cat, 512,
                                                         384 * 512, 16, 384 * 512);

  // mega: [z | pad | t_img | s_img] @ [Wp1_top || Wp1_bot || Wi1 || Wc1_top]
  gemm_atom<1><<<dim3(32, 7, 1), 256, 0, stream>>>(A_cat, 512, Wcat, 512, 4096, 16, 16,
                                                   Facc, 4096, 0);
  k_buildH1T1<<<dim3(29696 * 128 / 256), 256, 0, stream>>>(Facc, t_attr, obj, negat,
                                                           bp1, bi1, H1, T1);

  // D2: pair_fc L2 -> X + rowsq partials  (K=1024 -> nK=32), grid 230x7
  {
    Panel s0{H1, 1024, Wp2t, 1024, bp2, 800, 832, 32, X, 832, nullptr, nullptr, 7, 0};
    gemm128<1><<<dim3(1610), 256, 0, stream>>>(s0, s0, 1 << 30, rsqP16, 29440,
                                               nullptr, nullptr, nullptr);
  }
  k_rs<<<dim3(115), 256, 0, stream>>>(rsqP16, 29440, rsP);

  // D3: compo L1 (K=832, rs+S, N=896, 230x7) + img L2 (N=1024, 2x8)
  {
    Panel s0{X, 832, Wc1bt, 832, bc1, 800, 896, 26, H2, 896, rsP,
             Facc + 640 * 4096 + 3072, 7, 0};
    Panel s1{T1, 832, Wi2t, 832, bi2, 1000, 1024, 26, T2, 1024, nullptr, nullptr, 8, 29440};
    gemm128<0><<<dim3(1626), 256, 0, stream>>>(s0, s1, 1610, nullptr, 0,
                                               nullptr, nullptr, nullptr);
  }
  // D4: compo L2 (K=896 -> nK=28, N=1024, 230x8)
  {
    Panel s0{H2, 896, Wc2t, 896, bc2, 1000, 1024, 28, H3, 1024, nullptr, nullptr, 8, 0};
    gemm128<0><<<dim3(1840), 256, 0, stream>>>(s0, s0, 1 << 30, nullptr, 0,
                                               nullptr, nullptr, nullptr);
  }
  // D5: compo L3 (theta+neg, 230x7) + img L3 (targets, 2x7), f32 out + rowsq
  {
    Panel s0{H3, 1024, Wc3t, 1024, bc3, 800, 800, 32, nullptr, 800, nullptr, nullptr, 7, 0};
    Panel s1{T2, 1024, Wi3t, 1024, bi3, 800, 800, 32, nullptr, 800, nullptr, nullptr, 7, 29440};
    gemm128<3><<<dim3(1624), 256, 0, stream>>>(s0, s1, 1610, rsqC16, 29696,
                                               cTheta, cNeg, cTgt);
  }
  k_norm3<<<dim3(29696), 256, 0, stream>>>(cTheta, cNeg, cTgt, rsqC16, 29696);
}

// Round 14
// 661.850 us; speedup vs baseline: 1.2068x; 1.0653x over previous
//
#include <hip/hip_runtime.h>

// ---------------------------------------------------------------------------
// GAE_IR_79499844649397. Atomic-free pipeline.
// Big GEMMs: 128x128 tile, 4 waves, BK=32, LDS 32KB dbuf + vmcnt(4),
// slot-XOR swizzle, __launch_bounds__(256,4), XCD chunked swizzle.
// SAGE: split-K z=8/16. Prep merged into ONE launch with 64x64 vectorized
// transpose-packs (16 elems/thread, 32B contiguous writes).
// ---------------------------------------------------------------------------

typedef unsigned short u16;
typedef __bf16 bf16x8 __attribute__((ext_vector_type(8)));
typedef float f32x4 __attribute__((ext_vector_type(4)));

__device__ inline u16 f2bf_u(float f) {
  union { float f; unsigned u; } a; a.f = f;
  unsigned u = a.u + 0x7fffu + ((a.u >> 16) & 1u);   // RNE
  return (u16)(u >> 16);
}
__device__ inline float bf2f_u(u16 h) {
  union { unsigned u; float f; } a; a.u = ((unsigned)h) << 16; return a.f;
}

#define GLOAD16(gptr, lptr)                                                   \
  __builtin_amdgcn_global_load_lds(                                           \
      (__attribute__((address_space(1))) void*)(gptr),                        \
      (__attribute__((address_space(3))) void*)(lptr), 16, 0, 0)

#define BAR  __builtin_amdgcn_s_barrier()
#define LGKM0 asm volatile("s_waitcnt lgkmcnt(0)" ::: "memory")
#define VMC4 asm volatile("s_waitcnt vmcnt(4)" ::: "memory")
#define VMC0 asm volatile("s_waitcnt vmcnt(0)" ::: "memory")

struct Panel {
  const u16* A; int lda;
  const u16* B; int ldb;
  const float* bias; int biasN;
  int N; int nK;               // nK in units of 32
  void* out; int ldc;
  const float* rsVec;          // optional per-row scale (pre-rsqrt'd)
  const float* addS;           // optional gathered row-add (f32, ld 4096)
  int gx;                      // col-blocks (N tiles of 128)
  int rowG0;                   // global row offset of this panel
};

// MODE 0: bf16 out, v = relu(acc*rs + bias + S[b])
// MODE 1: bf16 out + bias, + rowsq partials
// MODE 3: f32 out + bias, 3-range remap + rowsq partials
template <int MODE>
__global__ __launch_bounds__(256, 4) void gemm128(
    Panel p0, Panel p1, int c0,
    float* __restrict__ rsPart, int rsLd,
    float* __restrict__ cTheta, float* __restrict__ cNeg, float* __restrict__ cTgt) {
  __shared__ u16 As[2][4096];   // [128][32] x2
  __shared__ u16 Bs[2][4096];

  // chunked-bijective XCD swizzle (1-D grid)
  const int nwg = gridDim.x;
  const int orig = blockIdx.x;
  const int q = nwg >> 3, r = nwg & 7, xcd = orig & 7;
  const int basewg = (xcd < r) ? xcd * (q + 1) : r * (q + 1) + (xcd - r) * q;
  const int wg = basewg + (orig >> 3);

  Panel P; int pby, pbx;
  if (wg < c0) { P = p0; pby = wg / p0.gx; pbx = wg - pby * p0.gx; }
  else { P = p1; const int w2 = wg - c0; pby = w2 / p1.gx; pbx = w2 - pby * p1.gx; }
  const int m0 = pby << 7, n0 = pbx << 7;

  const int tid = threadIdx.x;
  const int wave = tid >> 6, lane = tid & 63;
  const int lr = lane & 15, lg = lane >> 4;
  const int wr = wave >> 1, wc = wave & 1;

  f32x4 acc[4][4] = {};

  // staging with slot-XOR swizzle: LDS[row][sc] = G[row][sc ^ ((row>>1)&3)]
  const int r0 = tid >> 2, sc0 = tid & 3;
  const size_t aOff  = (size_t)(m0 + r0) * P.lda + ((sc0 ^ ((r0 >> 1) & 3)) << 3);
  const size_t aOff1 = (size_t)(m0 + r0 + 64) * P.lda + ((sc0 ^ (((r0 + 64) >> 1) & 3)) << 3);
  const size_t bOff  = (size_t)(n0 + r0) * P.ldb + ((sc0 ^ ((r0 >> 1) & 3)) << 3);
  const size_t bOff1 = (size_t)(n0 + r0 + 64) * P.ldb + ((sc0 ^ (((r0 + 64) >> 1) & 3)) << 3);
  const int lL = (r0 * 4 + sc0) << 4;   // byte offset within buffer (linear dest)

  auto stage = [&](int kt, int b) {
    const int k0 = kt << 5;
    GLOAD16(P.A + aOff + k0, (char*)As[b] + lL);
    GLOAD16(P.A + aOff1 + k0, (char*)As[b] + lL + 4096);
    GLOAD16(P.B + bOff + k0, (char*)Bs[b] + lL);
    GLOAD16(P.B + bOff1 + k0, (char*)Bs[b] + lL + 4096);
  };

  const int nK = P.nK;
  stage(0, 0);
  for (int kt = 0; kt < nK; ++kt) {
    const int cb = kt & 1;
    if (kt + 1 < nK) { stage(kt + 1, cb ^ 1); VMC4; }
    else { VMC0; }
    BAR;

    bf16x8 af[4], bv[4];
#pragma unroll
    for (int m = 0; m < 4; ++m) {
      const int row = (wr << 6) + (m << 4) + lr;
      af[m] = *(const bf16x8*)(&As[cb][row * 32 + ((lg ^ ((row >> 1) & 3)) << 3)]);
    }
#pragma unroll
    for (int n = 0; n < 4; ++n) {
      const int row = (wc << 6) + (n << 4) + lr;
      bv[n] = *(const bf16x8*)(&Bs[cb][row * 32 + ((lg ^ ((row >> 1) & 3)) << 3)]);
    }
#pragma unroll
    for (int m = 0; m < 4; ++m)
#pragma unroll
      for (int n = 0; n < 4; ++n)
        acc[m][n] = __builtin_amdgcn_mfma_f32_16x16x32_bf16(af[m], bv[n], acc[m][n], 0, 0, 0);

    LGKM0;
    BAR;
  }

  const int gcb = n0 + (wc << 6);
  const int grb = m0 + (wr << 6) + (lg << 2);
#pragma unroll
  for (int m = 0; m < 4; ++m) {
#pragma unroll
    for (int rr = 0; rr < 4; ++rr) {
      const int grow = grb + (m << 4) + rr;
      const int growG = P.rowG0 + grow;
      float ss = 0.f;
      float rs = 1.f;
      const float* Sp = nullptr;
      if (MODE == 0) {
        if (P.rsVec) rs = P.rsVec[growG];
        if (P.addS) {
          int bv2 = (growG < 256) ? growG : (growG - 256) / 114;
          Sp = P.addS + (size_t)bv2 * 4096;
        }
      }
#pragma unroll
      for (int n = 0; n < 4; ++n) {
        const int gc = gcb + (n << 4) + lr;
        if (gc >= P.N) continue;
        float v = acc[m][n][rr];
        if (MODE == 0) {
          v *= rs;
          if (gc < P.biasN) v += P.bias[gc];
          if (Sp) v += Sp[gc];
          v = fmaxf(v, 0.f);
          ((u16*)P.out)[(size_t)grow * P.ldc + gc] = f2bf_u(v);
        } else if (MODE == 1) {
          if (gc < P.biasN) v += P.bias[gc];
          ((u16*)P.out)[(size_t)grow * P.ldc + gc] = f2bf_u(v);
          ss += v * v;
        } else {
          if (gc < P.biasN) v += P.bias[gc];
          float* op = (growG < 256) ? cTheta + (size_t)growG * 800
                    : (growG < 29440) ? cNeg + (size_t)(growG - 256) * 800
                                      : cTgt + (size_t)(growG - 29440) * 800;
          op[gc] = v;
          ss += v * v;
        }
      }
      if (MODE == 1 || MODE == 3) {
        ss += __shfl_xor(ss, 1); ss += __shfl_xor(ss, 2);
        ss += __shfl_xor(ss, 4); ss += __shfl_xor(ss, 8);
        if (lr == 0) rsPart[(size_t)((pbx << 1) + wc) * rsLd + growG] = ss;
      }
    }
  }
}

// ---------------------------------------------------------------------------
// Small-M GEMM: 128x128, BK=32. STORE=1 plain store; else z-partial store.
// ---------------------------------------------------------------------------
template <int STORE>
__global__ __launch_bounds__(256) void gemm_atom(
    const u16* __restrict__ A, int lda, const u16* __restrict__ Bt, int ldb,
    int N, int nK, int ktChunk, float* __restrict__ Cf, int ldc, int zStride) {
  __shared__ u16 As[2][4096];
  __shared__ u16 Bs[2][4096];
  const int tid = threadIdx.x;
  const int wave = tid >> 6, lane = tid & 63;
  const int lr = lane & 15, lg = lane >> 4;
  const int wr = wave >> 1, wc = wave & 1;
  const int m0 = blockIdx.y << 7, n0 = blockIdx.x << 7;

  f32x4 acc[4][4] = {};

  const size_t aOff  = (size_t)(m0 + (tid >> 2)) * lda + ((tid & 3) << 3);
  const size_t aOff1 = aOff + (size_t)64 * lda;
  const size_t bOff  = (size_t)(n0 + (tid >> 2)) * ldb + ((tid & 3) << 3);
  const size_t bOff1 = bOff + (size_t)64 * ldb;

  const int kt0 = blockIdx.z * ktChunk;
  int ktEnd = kt0 + ktChunk; if (ktEnd > nK) ktEnd = nK;

  auto stage = [&](int kt, int b) {
    const int k0 = kt << 5;
    u16* Ad = &As[b][wave << 9];
    u16* Bd = &Bs[b][wave << 9];
    GLOAD16(A + aOff + k0, Ad);
    GLOAD16(A + aOff1 + k0, Ad + 2048);
    GLOAD16(Bt + bOff + k0, Bd);
    GLOAD16(Bt + bOff1 + k0, Bd + 2048);
  };

  if (kt0 < ktEnd) stage(kt0, 0);
  for (int kt = kt0; kt < ktEnd; ++kt) {
    const int cb = (kt - kt0) & 1;
    if (kt + 1 < ktEnd) {
      stage(kt + 1, cb ^ 1);
      VMC4;
    } else {
      VMC0;
    }
    BAR;
    asm volatile("" ::: "memory");

    bf16x8 af[4], bvv[4];
#pragma unroll
    for (int m = 0; m < 4; ++m)
      af[m] = *(const bf16x8*)(&As[cb][(((wr << 6) + (m << 4) + lr) << 5) + (lg << 3)]);
#pragma unroll
    for (int n = 0; n < 4; ++n)
      bvv[n] = *(const bf16x8*)(&Bs[cb][(((wc << 6) + (n << 4) + lr) << 5) + (lg << 3)]);
#pragma unroll
    for (int m = 0; m < 4; ++m)
#pragma unroll
      for (int n = 0; n < 4; ++n)
        acc[m][n] = __builtin_amdgcn_mfma_f32_16x16x32_bf16(af[m], bvv[n], acc[m][n], 0, 0, 0);

    asm volatile("s_waitcnt lgkmcnt(0)" ::: "memory");
    BAR;
    asm volatile("" ::: "memory");
  }

  float* out = STORE ? Cf : (Cf + (size_t)blockIdx.z * zStride);
  const int gcb = n0 + (wc << 6);
  const int grb = m0 + (wr << 6) + (lg << 2);
#pragma unroll
  for (int m = 0; m < 4; ++m)
#pragma unroll
    for (int rr = 0; rr < 4; ++rr) {
      const int grow = grb + (m << 4) + rr;
#pragma unroll
      for (int n = 0; n < 4; ++n) {
        const int gc = gcb + (n << 4) + lr;
        if (gc < N) out[(size_t)grow * ldc + gc] = acc[m][n][rr];
      }
    }
}

// --------------------------- merged prep kernel ----------------------------
// Unified 64x64 transpose-pack jobs (splits + plain), then agg1, then cvt2.
struct PK {
  const float* srcA; const float* srcB; u16* dst;
  int splitK, Ktot, Ksrc, Nsrc, srcLd, dstLd, Npad, nTiles, tile0;
};
struct PKs { PK j[12]; };

#define PREP_PACK_TILES 4992

__global__ __launch_bounds__(256) void k_prep(
    PKs J,
    const int* __restrict__ es, const int* __restrict__ ed,
    const float* __restrict__ nodes,
    const float* __restrict__ t_img, const float* __restrict__ s_img,
    u16* __restrict__ Agp, u16* __restrict__ dstT, u16* __restrict__ dstS) {
  __shared__ float t[64][65];
  int b = blockIdx.x;
  const int tid = threadIdx.x;

  if (b < PREP_PACK_TILES) {
    int ji = 0;
#pragma unroll
    for (int jj = 1; jj < 12; ++jj)
      if (b >= J.j[jj].tile0) ji = jj;
    PK job = J.j[ji];
    const int local = b - job.tile0;
    const int kTile = local / job.nTiles, nTile = local - kTile * job.nTiles;
    const int k0 = kTile << 6, n0 = nTile << 6;
    const int blk = k0 / job.Ktot;            // 0 for plain jobs
    const int km0 = k0 - blk * job.Ktot;
    const float* src = (km0 < job.splitK)
        ? job.srcA + (size_t)km0 * job.srcLd
        : job.srcB + (size_t)(km0 - job.splitK) * job.srcLd;
    const bool lo = (blk == 2);

    const int rr = tid >> 4, cc = (tid & 15) << 2;
    const bool interior = (km0 + 64 <= job.Ksrc) && (n0 + 64 <= job.Nsrc);
#pragma unroll
    for (int i = 0; i < 4; ++i) {
      const int row = rr + (i << 4);
      float4 v;
      if (interior) {
        v = *(const float4*)(src + (size_t)row * job.srcLd + n0 + cc);
      } else {
        v.x = v.y = v.z = v.w = 0.f;
        if (km0 + row < job.Ksrc) {
          const float* sr = src + (size_t)row * job.srcLd + n0 + cc;
          if (n0 + cc + 0 < job.Nsrc) v.x = sr[0];
          if (n0 + cc + 1 < job.Nsrc) v.y = sr[1];
          if (n0 + cc + 2 < job.Nsrc) v.z = sr[2];
          if (n0 + cc + 3 < job.Nsrc) v.w = sr[3];
        }
      }
      t[row][cc] = v.x; t[row][cc + 1] = v.y; t[row][cc + 2] = v.z; t[row][cc + 3] = v.w;
    }
    __syncthreads();
    const int nr = tid >> 2, kc = (tid & 3) << 4;
    if (n0 + nr < job.Npad) {
      u16 o[16] __attribute__((aligned(16)));
#pragma unroll
      for (int jx = 0; jx < 16; ++jx) {
        float x = t[kc + jx][nr];
        u16 hb = f2bf_u(x);
        o[jx] = lo ? f2bf_u(x - bf2f_u(hb)) : hb;
      }
      u16* dp = job.dst + (size_t)(n0 + nr) * job.dstLd + k0 + kc;
      *(uint4*)dp = *(const uint4*)&o[0];
      *(uint4*)(dp + 8) = *(const uint4*)&o[8];
    }
    return;
  }
  b -= PREP_PACK_TILES;
  if (b < 384) {                      // aggpack1
    const int node = b;
    const int c = tid * 2;
    u16* row = Agp + (size_t)node * 3072;
    if (node >= 360) {
#pragma unroll
      for (int bb = 0; bb < 3; ++bb) { row[bb * 1024 + c] = 0; row[bb * 1024 + c + 1] = 0;
                                       row[bb * 1024 + 512 + c] = 0; row[bb * 1024 + 512 + c + 1] = 0; }
      return;
    }
    float a0 = 0.f, a1 = 0.f, cnt = 0.f;
    for (int e = 0; e < 1262; ++e) {
      if (ed[e] == node) {
        const float* xr = nodes + (size_t)es[e] * 512;
        a0 += xr[c]; a1 += xr[c + 1]; cnt += 1.f;
      }
    }
    float inv = 1.f / fmaxf(cnt, 1.f);
    a0 *= inv; a1 *= inv;
    float x0 = nodes[(size_t)node * 512 + c], x1 = nodes[(size_t)node * 512 + c + 1];
    u16 ah0 = f2bf_u(a0), ah1 = f2bf_u(a1);
    u16 al0 = f2bf_u(a0 - bf2f_u(ah0)), al1 = f2bf_u(a1 - bf2f_u(ah1));
    u16 xh0 = f2bf_u(x0), xh1 = f2bf_u(x1);
    u16 xl0 = f2bf_u(x0 - bf2f_u(xh0)), xl1 = f2bf_u(x1 - bf2f_u(xh1));
    row[c] = ah0; row[c + 1] = ah1; row[512 + c] = xh0; row[512 + c + 1] = xh1;
    row[1024 + c] = al0; row[1024 + c + 1] = al1; row[1536 + c] = xl0; row[1536 + c + 1] = xl1;
    row[2048 + c] = ah0; row[2048 + c + 1] = ah1; row[2560 + c] = xh0; row[2560 + c + 1] = xh1;
    return;
  }
  b -= 384;
  {                                   // cvt2
    const int idx = b * 256 + tid;    // < 65536
    const float* src = (idx < 32768) ? t_img : s_img;
    u16* dst = (idx < 32768) ? dstT : dstS;
    const int i = idx & 32767;
    float4 v = *(const float4*)(src + ((size_t)i << 2));
    ushort4 o;
    o.x = f2bf_u(v.x); o.y = f2bf_u(v.y); o.z = f2bf_u(v.z); o.w = f2bf_u(v.w);
    *(ushort4*)(dst + ((size_t)i << 2)) = o;
  }
}

// ---------------- SAGE aggregation layer-2 (atomic-free scan) --------------
__global__ void k_aggpack2(const int* __restrict__ es, const int* __restrict__ ed,
                           const float* __restrict__ Hf, u16* __restrict__ A2p) {
  const int node = blockIdx.x;              // 0..383
  const int c = threadIdx.x * 8;
  u16* row = A2p + (size_t)node * 12288;
  if (node >= 360) {
#pragma unroll
    for (int b = 0; b < 3; ++b)
      for (int j = 0; j < 8; ++j) { row[b * 4096 + c + j] = 0; row[b * 4096 + 2048 + c + j] = 0; }
    return;
  }
  float a[8] = {}; float cnt = 0.f;
  for (int e = 0; e < 1262; ++e) {
    if (ed[e] == node) {
      const float* hr = Hf + (size_t)es[e] * 2048 + c;
      float4 v0 = *(const float4*)hr, v1 = *(const float4*)(hr + 4);
      a[0] += v0.x; a[1] += v0.y; a[2] += v0.z; a[3] += v0.w;
      a[4] += v1.x; a[5] += v1.y; a[6] += v1.z; a[7] += v1.w;
      cnt += 1.f;
    }
  }
  float inv = 1.f / fmaxf(cnt, 1.f);
  const float* hx = Hf + (size_t)node * 2048 + c;
#pragma unroll
  for (int j = 0; j < 8; ++j) {
    float av = a[j] * inv, xv = hx[j];
    u16 ah = f2bf_u(av), xh = f2bf_u(xv);
    u16 al = f2bf_u(av - bf2f_u(ah)), xl = f2bf_u(xv - bf2f_u(xh));
    row[c + j] = ah; row[2048 + c + j] = xh;
    row[4096 + c + j] = al; row[6144 + c + j] = xl;
    row[8192 + c + j] = ah; row[10240 + c + j] = xh;
  }
}

// partial-sum + bias kernels
__global__ void k_relu_bias_f32(const float* __restrict__ acc, const float* __restrict__ bias,
                                float* __restrict__ out, int N, int total, int nz, int zs) {
  int idx = blockIdx.x * 256 + threadIdx.x;
  if (idx >= total) return;
  float s = 0.f;
  for (int z = 0; z < nz; ++z) s += acc[(size_t)z * zs + idx];
  out[idx] = fmaxf(s + bias[idx % N], 0.f);
}
__global__ void k_bias_bf16(const float* __restrict__ acc, const float* __restrict__ bias,
                            u16* __restrict__ out, int N, int total, int nz, int zs) {
  int idx = blockIdx.x * 256 + threadIdx.x;
  if (idx >= total) return;
  float s = 0.f;
  for (int z = 0; z < nz; ++z) s += acc[(size_t)z * zs + idx];
  out[idx] = f2bf_u(s + bias[idx % N]);
}

// H1[r][c<1000] = relu(F[a(r)][c] + G[115+o(r)][c] + bp1[c]); pad 0 to 1024.
// T1[rt][c<800] = relu(I1[rt][c] + bi1[c]); pad 0 to 832.
__global__ void k_buildH1T1(const float* __restrict__ Facc,
                            const int* __restrict__ t_attr, const int* __restrict__ obj,
                            const int* __restrict__ negat, const float* __restrict__ bp1,
                            const float* __restrict__ bi1,
                            u16* __restrict__ H1, u16* __restrict__ T1) {
  int idx = blockIdx.x * 256 + threadIdx.x;
  if (idx >= 29696 * 128) return;
  int r = idx >> 7, ch = idx & 127, c = ch << 3;
  if (r < 29440) {
    u16* dst = H1 + ((size_t)r << 10) + c;
    if (c >= 1000) { ushort4 z = {0,0,0,0}; *(ushort4*)dst = z; *(ushort4*)(dst + 4) = z; return; }
    int a, o;
    if (r < 256) { a = t_attr[r]; o = obj[r]; }
    else { int rr = r - 256; a = negat[rr]; o = obj[rr / 114]; }
    const float* Fa = Facc + (size_t)a * 4096 + c;
    const float* Go = Facc + (size_t)(115 + o) * 4096 + 1024 + c;
    const float* Bp = bp1 + c;
    ushort4 o0, o1;
    float4 f0 = *(const float4*)Fa, f1 = *(const float4*)(Fa + 4);
    float4 g0 = *(const float4*)Go, g1 = *(const float4*)(Go + 4);
    float4 b0 = *(const float4*)Bp, b1 = *(const float4*)(Bp + 4);
    o0.x = f2bf_u(fmaxf(f0.x + g0.x + b0.x, 0.f));
    o0.y = f2bf_u(fmaxf(f0.y + g0.y + b0.y, 0.f));
    o0.z = f2bf_u(fmaxf(f0.z + g0.z + b0.z, 0.f));
    o0.w = f2bf_u(fmaxf(f0.w + g0.w + b0.w, 0.f));
    o1.x = f2bf_u(fmaxf(f1.x + g1.x + b1.x, 0.f));
    o1.y = f2bf_u(fmaxf(f1.y + g1.y + b1.y, 0.f));
    o1.z = f2bf_u(fmaxf(f1.z + g1.z + b1.z, 0.f));
    o1.w = f2bf_u(fmaxf(f1.w + g1.w + b1.w, 0.f));
    *(ushort4*)dst = o0; *(ushort4*)(dst + 4) = o1;
  } else {
    int rt = r - 29440;
    if (ch >= 104) return;
    u16* dst = T1 + (size_t)rt * 832 + c;
    if (c >= 800) { ushort4 z = {0,0,0,0}; *(ushort4*)dst = z; *(ushort4*)(dst + 4) = z; return; }
    const float* I1 = Facc + (size_t)(384 + rt) * 4096 + 2048 + c;
    const float* Bi = bi1 + c;
    float4 f0 = *(const float4*)I1, f1 = *(const float4*)(I1 + 4);
    float4 b0 = *(const float4*)Bi, b1 = *(const float4*)(Bi + 4);
    ushort4 o0, o1;
    o0.x = f2bf_u(fmaxf(f0.x + b0.x, 0.f)); o0.y = f2bf_u(fmaxf(f0.y + b0.y, 0.f));
    o0.z = f2bf_u(fmaxf(f0.z + b0.z, 0.f)); o0.w = f2bf_u(fmaxf(f0.w + b0.w, 0.f));
    o1.x = f2bf_u(fmaxf(f1.x + b1.x, 0.f)); o1.y = f2bf_u(fmaxf(f1.y + b1.y, 0.f));
    o1.z = f2bf_u(fmaxf(f1.z + b1.z, 0.f)); o1.w = f2bf_u(fmaxf(f1.w + b1.w, 0.f));
    *(ushort4*)dst = o0; *(ushort4*)(dst + 4) = o1;
  }
}

// reduce 14 partials -> rs = rsqrt(sum)
__global__ void k_rs(const float* __restrict__ part, int nrows, float* __restrict__ rs) {
  int idx = blockIdx.x * 256 + threadIdx.x;
  if (idx >= nrows) return;
  float s = 0.f;
#pragma unroll
  for (int i = 0; i < 14; ++i) s += part[(size_t)i * nrows + idx];
  rs[idx] = rsqrtf(fmaxf(s, 1e-24f));
}

// scale the three f32 output regions; rs computed inline from 14 partials
__global__ void k_norm3(float* __restrict__ cTheta, float* __restrict__ cNeg,
                        float* __restrict__ cTgt, const float* __restrict__ part,
                        int nrows) {
  int r = blockIdx.x;
  float ssum = 0.f;
#pragma unroll
  for (int i = 0; i < 14; ++i) ssum += part[(size_t)i * nrows + r];
  float s = rsqrtf(fmaxf(ssum, 1e-24f));
  float* row = (r < 256) ? cTheta + (size_t)r * 800
             : (r < 29440) ? cNeg + (size_t)(r - 256) * 800
                           : cTgt + (size_t)(r - 29440) * 800;
  int c = threadIdx.x;
  if (c < 200) {
    float4 v = *(float4*)(row + (c << 2));
    v.x *= s; v.y *= s; v.z *= s; v.w *= s;
    *(float4*)(row + (c << 2)) = v;
  }
}

// ---------------------------------------------------------------------------
extern "C" void kernel_launch(void* const* d_in, const int* in_sizes, int n_in,
                              void* d_out, int out_size, void* d_ws, size_t ws_size,
                              hipStream_t stream) {
  const float* nodes = (const float*)d_in[0];
  const float* s_img = (const float*)d_in[1];
  const float* t_img = (const float*)d_in[2];
  const float* Wl1 = (const float*)d_in[3];
  const float* Wr1 = (const float*)d_in[4];
  const float* b1  = (const float*)d_in[5];
  const float* Wl2 = (const float*)d_in[6];
  const float* Wr2 = (const float*)d_in[7];
  const float* b2  = (const float*)d_in[8];
  const float* Wp1 = (const float*)d_in[9];
  const float* bp1 = (const float*)d_in[10];
  const float* Wp2 = (const float*)d_in[11];
  const float* bp2 = (const float*)d_in[12];
  const float* Wi1 = (const float*)d_in[13];
  const float* bi1 = (const float*)d_in[14];
  const float* Wi2 = (const float*)d_in[15];
  const float* bi2 = (const float*)d_in[16];
  const float* Wi3 = (const float*)d_in[17];
  const float* bi3 = (const float*)d_in[18];
  const float* Wc1 = (const float*)d_in[19];
  const float* bc1 = (const float*)d_in[20];
  const float* Wc2 = (const float*)d_in[21];
  const float* bc2 = (const float*)d_in[22];
  const float* Wc3 = (const float*)d_in[23];
  const float* bc3 = (const float*)d_in[24];
  const int* e_src = (const int*)d_in[25];
  const int* e_dst = (const int*)d_in[26];
  const int* t_attr = (const int*)d_in[27];
  const int* obj    = (const int*)d_in[28];
  const int* negat  = (const int*)d_in[29];
  (void)in_sizes; (void)n_in; (void)out_size; (void)ws_size;

  float* out = (float*)d_out;
  float* cTheta = out;
  float* cTgt = out + 204800;
  float* cNeg = out + 409600;

  char* p = (char*)d_ws;
  auto alloc = [&](size_t bytes) -> void* {
    char* r = p; p += (bytes + 255) & ~(size_t)255; return (void*)r;
  };
  u16* W1t   = (u16*)alloc(2048ull * 3072 * 2);
  u16* W2t   = (u16*)alloc(512ull * 12288 * 2);
  u16* Wp2t  = (u16*)alloc(1024ull * 1024 * 2);
  u16* Wc1bt = (u16*)alloc(1024ull * 832 * 2);
  u16* Wc2t  = (u16*)alloc(1024ull * 896 * 2);
  u16* Wc3t  = (u16*)alloc(1024ull * 1024 * 2);
  u16* Wi2t  = (u16*)alloc(1024ull * 832 * 2);
  u16* Wi3t  = (u16*)alloc(1024ull * 1024 * 2);
  u16* Wcat  = (u16*)alloc(4096ull * 512 * 2);
  u16* Agp   = (u16*)alloc(384ull * 3072 * 2);
  float* Hacc = (float*)alloc(8ull * 384 * 2048 * 4);
  float* Hf   = (float*)alloc(384ull * 2048 * 4);
  u16* A2p   = (u16*)alloc(384ull * 12288 * 2);
  float* Zacc = (float*)alloc(16ull * 384 * 512 * 4);
  u16* A_cat = (u16*)alloc(896ull * 512 * 2);
  float* Facc = (float*)alloc(896ull * 4096 * 4);
  u16* T1    = (u16*)alloc(256ull * 832 * 2);
  u16* T2    = (u16*)alloc(256ull * 1024 * 2);
  float* rsqP16 = (float*)alloc(16ull * 29440 * 4);
  float* rsqC16 = (float*)alloc(16ull * 29696 * 4);
  float* rsP = (float*)alloc(29440ull * 4);
  u16* H1 = (u16*)alloc(29440ull * 1024 * 2);
  u16* X  = (u16*)alloc(29440ull * 832 * 2);
  u16* H3 = (u16*)alloc(29440ull * 1024 * 2);
  u16* H2 = H1;   // [29440][896] aliases H1 (dead after D2)

  const int BIG = 1 << 28;
  // merged prep: 64x64 vectorized packs + agg1 + img converts (one launch)
  {
    PKs J;
    //            srcA            srcB  dst    splitK Ktot  Ksrc  Nsrc srcLd dstLd  Npad nT tile0
    J.j[0]  = {Wl1,             Wr1,  W1t,    512,  1024, 1024, 2048, 2048, 3072, 2048, 32, 0};
    J.j[1]  = {Wl2,             Wr2,  W2t,   2048,  4096, 4096,  512,  512, 12288, 512,  8, 1536};
    J.j[2]  = {Wp2,             Wp2,  Wp2t,   BIG,   BIG, 1000,  800,  800, 1024, 1024, 16, 3072};
    J.j[3]  = {Wc1 + 512 * 800, Wc1,  Wc1bt,  BIG,   BIG,  800,  800,  800,  832, 1024, 16, 3328};
    J.j[4]  = {Wc2,             Wc2,  Wc2t,   BIG,   BIG,  800, 1000, 1000,  896, 1024, 16, 3536};
    J.j[5]  = {Wc3,             Wc3,  Wc3t,   BIG,   BIG, 1000,  800,  800, 1024, 1024, 16, 3760};
    J.j[6]  = {Wi2,             Wi2,  Wi2t,   BIG,   BIG,  800, 1000, 1000,  832, 1024, 16, 4016};
    J.j[7]  = {Wi3,             Wi3,  Wi3t,   BIG,   BIG, 1000,  800,  800, 1024, 1024, 16, 4224};
    J.j[8]  = {Wp1,             Wp1,  Wcat,   BIG,   BIG,  512, 1000, 1000,  512, 1024, 16, 4480};
    J.j[9]  = {Wp1 + 512 * 1000, Wp1, Wcat + 1024 * 512, BIG, BIG, 512, 1000, 1000, 512, 1024, 16, 4608};
    J.j[10] = {Wi1,             Wi1,  Wcat + 2048 * 512, BIG, BIG, 512,  800,  800,  512, 1024, 16, 4736};
    J.j[11] = {Wc1,             Wc1,  Wcat + 3072 * 512, BIG, BIG, 512,  800,  800,  512, 1024, 16, 4864};
    k_prep<<<dim3(PREP_PACK_TILES + 384 + 256), 256, 0, stream>>>(
        J, e_src, e_dst, nodes, t_img, s_img,
        Agp, A_cat + 384 * 512, A_cat + 640 * 512);
  }

  // SAGE (split-K z=8 / z=16)
  gemm_atom<0><<<dim3(16, 3, 8), 256, 0, stream>>>(Agp, 3072, W1t, 3072, 2048, 96, 12,
                                                   Hacc, 2048, 384 * 2048);
  k_relu_bias_f32<<<dim3(384 * 2048 / 256), 256, 0, stream>>>(Hacc, b1, Hf, 2048,
                                                              384 * 2048, 8, 384 * 2048);
  k_aggpack2<<<dim3(384), 256, 0, stream>>>(e_src, e_dst, Hf, A2p);
  gemm_atom<0><<<dim3(4, 3, 16), 256, 0, stream>>>(A2p, 12288, W2t, 12288, 512, 384, 24,
                                                   Zacc, 512, 384 * 512);
  k_bias_bf16<<<dim3(384 * 512 / 256), 256, 0, stream>>>(Zacc, b2, A_cat, 512,
                                                         384 * 512, 16, 384 * 512);

  // mega: [z | pad | t_img | s_img] @ [Wp1_top || Wp1_bot || Wi1 || Wc1_top]
  gemm_atom<1><<<dim3(32, 7, 1), 256, 0, stream>>>(A_cat, 512, Wcat, 512, 4096, 16, 16,
                                                   Facc, 4096, 0);
  k_buildH1T1<<<dim3(29696 * 128 / 256), 256, 0, stream>>>(Facc, t_attr, obj, negat,
                                                           bp1, bi1, H1, T1);

  // D2: pair_fc L2 -> X + rowsq partials  (K=1024 -> nK=32), grid 230x7
  {
    Panel s0{H1, 1024, Wp2t, 1024, bp2, 800, 832, 32, X, 832, nullptr, nullptr, 7, 0};
    gemm128<1><<<dim3(1610), 256, 0, stream>>>(s0, s0, 1 << 30, rsqP16, 29440,
                                               nullptr, nullptr, nullptr);
  }
  k_rs<<<dim3(115), 256, 0, stream>>>(rsqP16, 29440, rsP);

  // D3: compo L1 (K=832, rs+S, N=896, 230x7) + img L2 (N=1024, 2x8)
  {
    Panel s0{X, 832, Wc1bt, 832, bc1, 800, 896, 26, H2, 896, rsP,
             Facc + 640 * 4096 + 3072, 7, 0};
    Panel s1{T1, 832, Wi2t, 832, bi2, 1000, 1024, 26, T2, 1024, nullptr, nullptr, 8, 29440};
    gemm128<0><<<dim3(1626), 256, 0, stream>>>(s0, s1, 1610, nullptr, 0,
                                               nullptr, nullptr, nullptr);
  }
  // D4: compo L2 (K=896 -> nK=28, N=1024, 230x8)
  {
    Panel s0{H2, 896, Wc2t, 896, bc2, 1000, 1024, 28, H3, 1024, nullptr, nullptr, 8, 0};
    gemm128<0><<<dim3(1840), 256, 0, stream>>>(s0, s0, 1 << 30, nullptr, 0,
                                               nullptr, nullptr, nullptr);
  }
  // D5: compo L3 (theta+neg, 230x7) + img L3 (targets, 2x7), f32 out + rowsq
  {
    Panel s0{H3, 1024, Wc3t, 1024, bc3, 800, 800, 32, nullptr, 800, nullptr, nullptr, 7, 0};
    Panel s1{T2, 1024, Wi3t, 1024, bi3, 800, 800, 32, nullptr, 800, nullptr, nullptr, 7, 29440};
    gemm128<3><<<dim3(1624), 256, 0, stream>>>(s0, s1, 1610, rsqC16, 29696,
                                               cTheta, cNeg, cTgt);
  }
  k_norm3<<<dim3(29696), 256, 0, stream>>>(cTheta, cNeg, cTgt, rsqC16, 29696);
}